// Round 16
// baseline (29955.731 us; speedup 1.0000x reference)
//
#include <hip/hip_runtime.h>
#include <math.h>

// DenseLSTMForecast: B=256, T=1024, H=128, FUTURE=32.
// R12 (2nd submit; round 15 hit GPUAcquisitionTimeout, never measured).
// R12: consumer-gated anti-deps + all-thread flag polling + barrier diet.
// R11 post-mortem (8483us, Occ 42%, VGPR 60, VALU 36%): occupancy doubled,
// step time UNCHANGED at 19.3k cy (R7=19.3k@2w, R10=38.4k@1w, R11=19.3k@4w,
// VALU busy ~7k constant). Floor is a serial latency chain, not issue BW
// and not wave count. Suspect (pre-committed branch A): helpers gate ring
// anti-deps on HEAD flag with slack 6, but helper->head chain = 4 stages;
// full-pipeline lag 4P+4RTT vs 6P forces head-lock-step, exposing flag
// RTT + L2 latency in every stage every step.
// Fixes:
//  (1) Anti-dep re-gate: RP2's only reader is c2 -> s1 waits c2>=t-6
//      (strict need t-7); RP3A/B only reader c5 -> s3,s4 wait c5>=t-6.
//      Head-gating kept only where head IS last reader (h-rings slack 14,
//      RO tail). Consumer flag >= head flag always => strictly looser, safe.
//  (2) All-thread flag polling (same addr -> wave-coalesced load); B1
//      barrier deleted in core/helper. LDS hazards re-audited: B2/B3(/B4)
//      still separate every cross-phase read/write. Head keeps loop-top
//      barrier (obuf out-write vs next-step overwrite race).
//  (3) ws layout/rings/indexing byte-identical to PASSING R11.
// Geometry: 1024-thr blocks (16 waves, 4 waves/SIMD), K-split dot w[64],
// 32 groups x 8 rows, 224 WGs, 7 stages (s0..s6) as before.
// Prediction: if chain was binding dur -> 5000-6500us, VALU 50-65%;
// null (>=8.2ms) -> flag topology exonerated, go co-resident stages.

#define TSEQ 1024
#define HH   128
#define TT   1056
#define THR  1024

// ---- ws dword offsets (identical to R7) ----
#define PLANES   0                 // 6 planes x [128 k][512 g] fp32
#define SCAL     393216            // xw1,xw2,xw3,bs1,bs2,bs3 (512 each)
#define WLIN     396288            // Wlin[0..384], [385]=b_lin, pad 512
#define XT       396800            // x transposed [1024][256]
#define RH1      658944            // h rings: [16][256][128] fp32
#define RH2      1183232
#define RH3      1707520
#define RO       2231808           // o ring [16][256] fp32
#define RP2      2235904           // partial rings: [8][256][512] fp32
#define RP3A     3284480
#define RP3B     4333056
#define FLAGS    5381632           // 224 x 32-dword lines
#define PREP_TOT 666112            // 658944 + 7168 (flags zeroing)

#define RH1_64 (RH1/2)
#define RH2_64 (RH2/2)
#define RH3_64 (RH3/2)

typedef unsigned long long u64;

__device__ __forceinline__ float sigmoidf_(float v) {
  return 1.0f / (1.0f + expf(-v));
}

__device__ __forceinline__ void wait_c(unsigned* p, unsigned tgt, unsigned& cached) {
  if (cached >= tgt) return;
  unsigned v = __hip_atomic_load(p, __ATOMIC_ACQUIRE, __HIP_MEMORY_SCOPE_AGENT);
  while (v < tgt) {
    __builtin_amdgcn_s_sleep(1);
    v = __hip_atomic_load(p, __ATOMIC_ACQUIRE, __HIP_MEMORY_SCOPE_AGENT);
  }
  cached = v;
}

// ---------------------------------------------------------------------------
__global__ void prep_kernel(const float* __restrict__ x,
                            const float* __restrict__ Wih1, const float* __restrict__ Whh1,
                            const float* __restrict__ bih1, const float* __restrict__ bhh1,
                            const float* __restrict__ Wih2, const float* __restrict__ Whh2,
                            const float* __restrict__ bih2, const float* __restrict__ bhh2,
                            const float* __restrict__ Wih3, const float* __restrict__ Whh3,
                            const float* __restrict__ bih3, const float* __restrict__ bhh3,
                            const float* __restrict__ Wlin, const float* __restrict__ blin,
                            float* __restrict__ ws) {
  int idx = blockIdx.x * 256 + threadIdx.x;
  if (idx < SCAL) {
    int p = idx >> 16;            // plane
    int rem = idx & 65535;
    int k = rem >> 9, g = rem & 511;
    float v;
    switch (p) {
      case 0:  v = Whh1[g * HH + k];         break;
      case 1:  v = Wih2[g * 129 + 1 + k];    break;
      case 2:  v = Whh2[g * HH + k];         break;
      case 3:  v = Wih3[g * 257 + 1 + k];    break;
      case 4:  v = Wih3[g * 257 + 129 + k];  break;
      default: v = Whh3[g * HH + k];         break;
    }
    ws[idx] = v;
  } else if (idx < WLIN) {
    int r = idx - SCAL;
    float v;
    if      (r < 512)  v = Wih1[r];
    else if (r < 1024) v = Wih2[(r - 512) * 129];
    else if (r < 1536) v = Wih3[(r - 1024) * 257];
    else if (r < 2048) v = bih1[r - 1536] + bhh1[r - 1536];
    else if (r < 2560) v = bih2[r - 2048] + bhh2[r - 2048];
    else               v = bih3[r - 2560] + bhh3[r - 2560];
    ws[idx] = v;
  } else if (idx < XT) {
    int j = idx - WLIN;
    ws[idx] = (j < 385) ? Wlin[j] : (j == 385 ? blin[0] : 0.0f);
  } else if (idx < RH1) {
    int j = idx - XT;
    int t = j >> 8, r = j & 255;
    ws[idx] = x[r * TSEQ + t];
  } else if (idx < PREP_TOT) {
    ws[FLAGS + (idx - RH1)] = 0.0f;   // zero flag lines (ws is poisoned)
  }
}

// ---------------------------------------------------------------------------
// Half-K dot: 64 of 128 k-values, 8 rows. acc[a] = sum_k w[k]*hbuf[a][kh*64+k].
__device__ __forceinline__ void dot64(const float* __restrict__ w,
                                      const float* __restrict__ hb,
                                      float acc[8]) {
  #pragma unroll
  for (int k4 = 0; k4 < 16; ++k4) {
    const float w0 = w[4 * k4], w1 = w[4 * k4 + 1];
    const float w2 = w[4 * k4 + 2], w3 = w[4 * k4 + 3];
    #pragma unroll
    for (int a = 0; a < 8; ++a) {
      const float4 h4 = *(const float4*)&hb[a * HH + k4 * 4];
      acc[a] = fmaf(w0, h4.x, fmaf(w1, h4.y, fmaf(w2, h4.z, fmaf(w3, h4.w, acc[a]))));
    }
  }
}

// ---------------------------------------------------------------------------
// Core stage: gates = Whh*h_own (K-split) + [partials or x-term]; act; publish.
// DRH: dword offset of destination h ring.
template <int SSELF, int SWA, int SWB, int NP, int XF, int PB, int PR1, int PR2, int DRH>
__device__ void core_stage(float* __restrict__ wsm, char* SB, int g) {
  const int tid = threadIdx.x;              // [0,1024)
  const int r0 = g * 8;
  float* gs   = (float*)SB;                 // [8][2][512] = 32768 B
  float* hown = (float*)(SB + 32768);       // [8][128] = 4096 B

  unsigned* flagb = (unsigned*)wsm + FLAGS;
  unsigned* Fself = flagb + (size_t)(SSELF * 32 + g) * 32;
  unsigned* Fh    = flagb + (size_t)(6 * 32 + g) * 32;
  unsigned* FA = (SWA >= 0) ? flagb + (size_t)(SWA * 32 + g) * 32 : nullptr;
  unsigned* FB = (SWB >= 0) ? flagb + (size_t)(SWB * 32 + g) * 32 : nullptr;
  unsigned ca = 0, cb = 0, ch = 0;

  // dot role: (col, k-half)
  const int col = tid & 511, kh = tid >> 9;
  float w[64];
  #pragma unroll
  for (int k = 0; k < 64; ++k)
    w[k] = wsm[(size_t)PB * 65536 + (size_t)(kh * 64 + k) * 512 + col];

  // activation role: unit (row, u); gate cols {u,128+u,256+u,384+u}
  const int row = tid >> 7, u = tid & 127;
  float xw4[4], bs4[4];
  if (XF) {
    #pragma unroll
    for (int q = 0; q < 4; ++q) {
      xw4[q] = wsm[SCAL + q * 128 + u];
      bs4[q] = wsm[SCAL + 1536 + q * 128 + u];
    }
  }

  hown[tid & 1023] = 0.f;                   // 8*128 = 1024 = blockDim
  float cst = 0.f;
  __syncthreads();

  for (int t = 0; t < TT; ++t) {
    // all-thread polling (same addresses -> wave-coalesced); no barrier:
    // every LDS hazard is still separated by B2/B3 below.
    if constexpr (SWA >= 0) wait_c(FA, (unsigned)(t + 1), ca);
    if constexpr (SWB >= 0) wait_c(FB, (unsigned)(t + 1), cb);
    {
      unsigned ht = (t >= 15) ? (unsigned)(t - 14) : 0u;
      if (XF && t >= TSEQ && (unsigned)t > ht) ht = (unsigned)t;
      if (ht) wait_c(Fh, ht, ch);
    }
    const int slot = t & 15;

    // activation-role prefetch: issue ring/x loads early, consume after B2.
    float pa[4], pb[4], xr;
    if constexpr (NP >= 1) {
      #pragma unroll
      for (int q = 0; q < 4; ++q) {
        unsigned uu = __hip_atomic_load(
            (unsigned*)wsm + PR1 + (size_t)(t & 7) * 131072 +
                (size_t)(r0 + row) * 512 + q * 128 + u,
            __ATOMIC_RELAXED, __HIP_MEMORY_SCOPE_AGENT);
        pa[q] = __builtin_bit_cast(float, uu);
      }
    }
    if constexpr (NP == 2) {
      #pragma unroll
      for (int q = 0; q < 4; ++q) {
        unsigned uu = __hip_atomic_load(
            (unsigned*)wsm + PR2 + (size_t)(t & 7) * 131072 +
                (size_t)(r0 + row) * 512 + q * 128 + u,
            __ATOMIC_RELAXED, __HIP_MEMORY_SCOPE_AGENT);
        pb[q] = __builtin_bit_cast(float, uu);
      }
    }
    if (XF) {
      if (t < TSEQ) {
        xr = wsm[XT + (size_t)t * 256 + r0 + row];
      } else {
        unsigned uu = __hip_atomic_load(
            (unsigned*)wsm + RO + (size_t)((t - 1) & 15) * 256 + r0 + row,
            __ATOMIC_RELAXED, __HIP_MEMORY_SCOPE_AGENT);
        xr = __builtin_bit_cast(float, uu);
      }
    }

    // half-K dot on own h (hown(t-1) ordered by previous step's B3)
    float acc[8] = {0.f, 0.f, 0.f, 0.f, 0.f, 0.f, 0.f, 0.f};
    dot64(w, hown + kh * 64, acc);
    #pragma unroll
    for (int a = 0; a < 8; ++a) gs[a * 1024 + kh * 512 + col] = acc[a];
    __syncthreads();                 // B2: half-sums visible

    // activation: 1 unit/thread; combine halves + add-terms; publish h
    {
      float gv[4];
      #pragma unroll
      for (int q = 0; q < 4; ++q) {
        const int c0 = q * 128 + u;
        float add;
        if constexpr (NP == 0)      add = fmaf(xw4[q], xr, bs4[q]);
        else if constexpr (NP == 1) add = pa[q];
        else                        add = pa[q] + pb[q];
        gv[q] = gs[row * 1024 + c0] + gs[row * 1024 + 512 + c0] + add;
      }
      const float c = sigmoidf_(gv[1]) * cst + sigmoidf_(gv[0]) * tanhf(gv[2]);
      cst = c;
      const float h = sigmoidf_(gv[3]) * tanhf(c);
      hown[row * HH + u] = h;
      __hip_atomic_store(
          (unsigned*)wsm + DRH + (size_t)slot * 32768 + (size_t)(r0 + row) * 128 + u,
          __builtin_bit_cast(unsigned, h),
          __ATOMIC_RELAXED, __HIP_MEMORY_SCOPE_AGENT);
    }
    __syncthreads();                 // B3: hown visible, stores drained
    if (tid == 0)
      __hip_atomic_fetch_add(Fself, 1u, __ATOMIC_RELAXED, __HIP_MEMORY_SCOPE_AGENT);
  }
}

// ---------------------------------------------------------------------------
// Helper stage: partial = [x-term+bias if XF] + Wpart * h_src(t) (K-split);
// combine halves via LDS; publish to partial ring.
// SC: CONSUMER stage id for the anti-dep (RP slot reader) — re-gated from
// head (4-hop chain, slack 6) to the direct consumer (1 hop, slack 6).
// Strict need: consumer >= t-7; we wait >= t-6 (margin 1). XF helpers still
// need head >= t for the RO feedback in the tail (t >= TSEQ).
template <int SSELF, int SW, int SC, int XF, int PB, int SI, int SRH64, int DRP>
__device__ void helper_stage(float* __restrict__ wsm, char* SB, int g) {
  const int tid = threadIdx.x;
  const int r0 = g * 8;
  float* ps  = (float*)SB;                  // [8][2][512] = 32768 B
  float* hin = (float*)(SB + 32768);        // [8][128] = 4096 B
  float* xs  = (float*)(SB + 36864);        // [8]

  u64* ws64 = (u64*)wsm;
  unsigned* flagb = (unsigned*)wsm + FLAGS;
  unsigned* Fself = flagb + (size_t)(SSELF * 32 + g) * 32;
  unsigned* Fw    = flagb + (size_t)(SW * 32 + g) * 32;
  unsigned* Fc    = flagb + (size_t)(SC * 32 + g) * 32;
  unsigned* Fhd   = flagb + (size_t)(6 * 32 + g) * 32;
  unsigned cw = 0, cc = 0, chd = 0;

  const int col = tid & 511, kh = tid >> 9;
  float w[64];
  #pragma unroll
  for (int k = 0; k < 64; ++k)
    w[k] = wsm[(size_t)PB * 65536 + (size_t)(kh * 64 + k) * 512 + col];
  const float xwv = XF ? wsm[SCAL + SI * 512 + col] : 0.f;
  const float bsv = XF ? wsm[SCAL + 1536 + SI * 512 + col] : 0.f;
  __syncthreads();

  for (int t = 0; t < TT; ++t) {
    // all-thread polling; no barrier (hazards covered by B2/B3/B4)
    wait_c(Fw, (unsigned)(t + 1), cw);
    if (t >= 7) wait_c(Fc, (unsigned)(t - 6), cc);
    if (XF && t >= TSEQ) wait_c(Fhd, (unsigned)t, chd);
    const int slot = t & 15;

    if (XF) {
      if (tid < 8) {
        float xv;
        if (t < TSEQ) {
          xv = wsm[XT + (size_t)t * 256 + r0 + tid];
        } else {
          unsigned uu = __hip_atomic_load(
              (unsigned*)wsm + RO + (size_t)((t - 1) & 15) * 256 + r0 + tid,
              __ATOMIC_RELAXED, __HIP_MEMORY_SCOPE_AGENT);
          xv = __builtin_bit_cast(float, uu);
        }
        xs[tid] = xv;
      }
    }
    // stage h_src(t): 512 u64 / first 512 threads
    if (tid < 512) {
      const int a = tid >> 6, up = tid & 63;
      u64 v = __hip_atomic_load(
          ws64 + SRH64 + (size_t)slot * 16384 + (size_t)(r0 + a) * 64 + up,
          __ATOMIC_RELAXED, __HIP_MEMORY_SCOPE_AGENT);
      *(u64*)&hin[a * HH + up * 2] = v;
    }
    __syncthreads();                 // B2: hin (and xs) visible

    float acc[8] = {0.f, 0.f, 0.f, 0.f, 0.f, 0.f, 0.f, 0.f};
    dot64(w, hin + kh * 64, acc);
    #pragma unroll
    for (int a = 0; a < 8; ++a) ps[a * 1024 + kh * 512 + col] = acc[a];
    __syncthreads();                 // B3: half-sums visible

    // combine + publish: 4096 values / 1024 thr = 4 each (same col, rows +2)
    #pragma unroll
    for (int i = 0; i < 4; ++i) {
      const int a = kh + i * 2;             // 0..7
      float v = ps[a * 1024 + col] + ps[a * 1024 + 512 + col];
      if (XF) v += fmaf(xwv, xs[a], bsv);
      __hip_atomic_store(
          (unsigned*)wsm + DRP + (size_t)(t & 7) * 131072 + (size_t)(r0 + a) * 512 + col,
          __builtin_bit_cast(unsigned, v),
          __ATOMIC_RELAXED, __HIP_MEMORY_SCOPE_AGENT);
    }
    __syncthreads();                 // B4: ring stores drained
    if (tid == 0)
      __hip_atomic_fetch_add(Fself, 1u, __ATOMIC_RELAXED, __HIP_MEMORY_SCOPE_AGENT);
  }
}

// ---------------------------------------------------------------------------
__device__ void head_stage(float* __restrict__ wsm, char* SB, int g,
                           float* __restrict__ out) {
  const int tid = threadIdx.x;
  const int r0 = g * 8;
  float* hin  = (float*)SB;                 // [3][8][128] = 12288 B
  float* obuf = (float*)(SB + 12288);       // [8][32]

  u64* ws64 = (u64*)wsm;
  unsigned* flagb = (unsigned*)wsm + FLAGS;
  unsigned* Fself = flagb + (size_t)(6 * 32 + g) * 32;
  unsigned* Fc3   = flagb + (size_t)(5 * 32 + g) * 32;
  unsigned c3c = 0;

  const int row = (tid >> 6) & 7, lane = tid & 63;
  float wlr[6];
  #pragma unroll
  for (int q = 0; q < 6; ++q) wlr[q] = wsm[WLIN + 1 + lane + 64 * q];
  const float wl0 = wsm[WLIN];
  const float blv = wsm[WLIN + 385];
  float xv = wsm[XT + r0 + row];

  for (int t = 0; t < TT; ++t) {
    wait_c(Fc3, (unsigned)(t + 1), c3c);     // all-thread poll
    __syncthreads();                 // B1: keeps out-write(t-1) ordered
    const int slot = t & 15;         //     before obuf overwrite (t&31 wrap)

    #pragma unroll
    for (int i = 0; i < 2; ++i) {
      const int idx = tid + i * 1024;       // 0..2047, use 0..1535
      if (idx < 1536) {
        const int s = idx >> 9, rem = idx & 511;
        const int a = rem >> 6, up = rem & 63;
        const size_t base = (s == 0) ? (size_t)RH1_64 : (s == 1) ? (size_t)RH2_64 : (size_t)RH3_64;
        u64 v = __hip_atomic_load(
            ws64 + base + (size_t)slot * 16384 + (size_t)(r0 + a) * 64 + up,
            __ATOMIC_RELAXED, __HIP_MEMORY_SCOPE_AGENT);
        *(u64*)&hin[(s * 8 + a) * HH + up * 2] = v;
      }
    }
    __syncthreads();                 // B2

    if (tid < 512) {
      float s = 0.f;
      #pragma unroll
      for (int q = 0; q < 6; ++q) {
        const int j = lane + 64 * q;        // 0..383
        const int si = j >> 7, uu = j & 127;
        s = fmaf(wlr[q], hin[(si * 8 + row) * HH + uu], s);
      }
      #pragma unroll
      for (int off = 32; off > 0; off >>= 1) s += __shfl_down(s, off, 64);
      if (lane == 0) {
        const float o = s + fmaf(wl0, xv, blv);
        obuf[row * 32 + (t & 31)] = o;
        __hip_atomic_store((unsigned*)wsm + RO + (size_t)slot * 256 + r0 + row,
                           __builtin_bit_cast(unsigned, o),
                           __ATOMIC_RELAXED, __HIP_MEMORY_SCOPE_AGENT);
        xv = (t + 1 < TSEQ) ? wsm[XT + (size_t)(t + 1) * 256 + r0 + row] : o;
      }
    }
    __syncthreads();                 // B3: o-store + obuf drained
    if (tid == 0)
      __hip_atomic_fetch_add(Fself, 1u, __ATOMIC_RELAXED, __HIP_MEMORY_SCOPE_AGENT);

    if ((t & 31) == 31) {
      const int tb = t - 31;
      if (tid < 256) {
        const int a = tid >> 5, m = tid & 31;
        out[(size_t)(r0 + a) * TT + tb + m] = obuf[a * 32 + m];
      }
    }
  }
}

// ---------------------------------------------------------------------------
__global__ __launch_bounds__(1024)
void lstm_kernel(float* __restrict__ wsm, float* __restrict__ out) {
  __shared__ __align__(16) char SB[36992];
  const int s = blockIdx.x >> 5, g = blockIdx.x & 31;
  switch (s) {
    case 0: core_stage<0, -1, -1, 0, 1, 0, 0, 0, RH1>(wsm, SB, g); break;
    case 1: helper_stage<1, 0, 2, 1, 1, 1, RH1_64, RP2>(wsm, SB, g); break;
    case 2: core_stage<2, 1, -1, 1, 0, 2, RP2, 0, RH2>(wsm, SB, g); break;
    case 3: helper_stage<3, 0, 5, 1, 3, 2, RH1_64, RP3A>(wsm, SB, g); break;
    case 4: helper_stage<4, 2, 5, 0, 4, 0, RH2_64, RP3B>(wsm, SB, g); break;
    case 5: core_stage<5, 3, 4, 2, 0, 5, RP3A, RP3B, RH3>(wsm, SB, g); break;
    default: head_stage(wsm, SB, g, out); break;
  }
}

// ---------------------------------------------------------------------------
extern "C" void kernel_launch(void* const* d_in, const int* in_sizes, int n_in,
                              void* d_out, int out_size, void* d_ws, size_t ws_size,
                              hipStream_t stream) {
  const float* x    = (const float*)d_in[0];
  const float* Wih1 = (const float*)d_in[1];
  const float* Whh1 = (const float*)d_in[2];
  const float* bih1 = (const float*)d_in[3];
  const float* bhh1 = (const float*)d_in[4];
  const float* Wih2 = (const float*)d_in[5];
  const float* Whh2 = (const float*)d_in[6];
  const float* bih2 = (const float*)d_in[7];
  const float* bhh2 = (const float*)d_in[8];
  const float* Wih3 = (const float*)d_in[9];
  const float* Whh3 = (const float*)d_in[10];
  const float* bih3 = (const float*)d_in[11];
  const float* bhh3 = (const float*)d_in[12];
  const float* Wlin = (const float*)d_in[13];
  const float* blin = (const float*)d_in[14];
  float* ws  = (float*)d_ws;
  float* out = (float*)d_out;

  prep_kernel<<<PREP_TOT / 256, 256, 0, stream>>>(
      x, Wih1, Whh1, bih1, bhh1, Wih2, Whh2, bih2, bhh2,
      Wih3, Whh3, bih3, bhh3, Wlin, blin, ws);
  lstm_kernel<<<224, THR, 0, stream>>>(ws, out);
}

// Round 17
// 8305.099 us; speedup vs baseline: 3.6069x; 3.6069x over previous
//
#include <hip/hip_runtime.h>
#include <math.h>

// DenseLSTMForecast: B=256, T=1024, H=128, FUTURE=32.
// R13: R11 (verified 8483us) + consumer-gated anti-deps ONLY.
// R12 post-mortem (29956us, VALU 10.3%): all-thread flag polling = 16
// waves/block x 224 blocks spinning acquire-loads on shared L2 flag lines
// -> contention serialized everything. Lesson: tid0-poll + barrier
// broadcast is the right pattern; never multi-wave-spin shared flags.
// R12 also bundled two variables; R13 isolates the anti-dep re-gate:
//  - helpers gate RP ring anti-dep on the DIRECT consumer (c2 for s1,
//    c5 for s3/s4) >= t-6 (1 hop, strict need t-7), instead of head
//    (4-hop chain). Chain-compression theory: skew/hop ~ (work+RTT)/P
//    ~ 2 steps; head-gating demands 4 hops in 6 slack -> compressed
//    lock-step exposes flag RTT per stage = the 19.3k cy/step floor
//    (R7@2w = R11@4w = 19.3k, VALU busy ~7k const).
//  - cores keep head-gating for h rings (head is the LAGGING reader;
//    s1/s3/s4 lead it, so head>=t-14 covers them). XF helpers keep
//    head>=t in tail for RO feedback.
// Everything else byte-identical to R11: 1024-thr blocks (16 waves,
// 4 waves/SIMD), K-split dot w[64], tid0 polling + B1 grant barrier,
// 32 groups x 8 rows, 224 WGs, 7 stages:
//   s0 c1-core   : g1 = xw1*x+b1 + Whh1*h1           -> RH1 ring
//   s1 c2-helper : p2 = xw2*x+b2 + Wih2[:,1:]*h1(t)  -> RP2 ring
//   s2 c2-core   : g2 = p2 + Whh2*h2                 -> RH2 ring
//   s3 c3-helperA: pA = xw3*x+b3 + Wih3[:,1:129]*h1  -> RP3A ring
//   s4 c3-helperB: pB = Wih3[:,129:257]*h2           -> RP3B ring
//   s5 c3-core   : g3 = pA+pB + Whh3*h3              -> RH3 ring
//   s6 head      : o = Wlin.[x,h1,h2,h3]+b           -> RO ring + out
// Prediction: binding -> 5000-6500us, VALU 50-60%; null (~8.4ms) ->
// forward handshake is the floor -> fuse stages next.

#define TSEQ 1024
#define HH   128
#define TT   1056
#define THR  1024

// ---- ws dword offsets (identical to R7) ----
#define PLANES   0                 // 6 planes x [128 k][512 g] fp32
#define SCAL     393216            // xw1,xw2,xw3,bs1,bs2,bs3 (512 each)
#define WLIN     396288            // Wlin[0..384], [385]=b_lin, pad 512
#define XT       396800            // x transposed [1024][256]
#define RH1      658944            // h rings: [16][256][128] fp32
#define RH2      1183232
#define RH3      1707520
#define RO       2231808           // o ring [16][256] fp32
#define RP2      2235904           // partial rings: [8][256][512] fp32
#define RP3A     3284480
#define RP3B     4333056
#define FLAGS    5381632           // 224 x 32-dword lines
#define PREP_TOT 666112            // 658944 + 7168 (flags zeroing)

#define RH1_64 (RH1/2)
#define RH2_64 (RH2/2)
#define RH3_64 (RH3/2)

typedef unsigned long long u64;

__device__ __forceinline__ float sigmoidf_(float v) {
  return 1.0f / (1.0f + expf(-v));
}

__device__ __forceinline__ void wait_c(unsigned* p, unsigned tgt, unsigned& cached) {
  if (cached >= tgt) return;
  unsigned v = __hip_atomic_load(p, __ATOMIC_ACQUIRE, __HIP_MEMORY_SCOPE_AGENT);
  while (v < tgt) {
    __builtin_amdgcn_s_sleep(1);
    v = __hip_atomic_load(p, __ATOMIC_ACQUIRE, __HIP_MEMORY_SCOPE_AGENT);
  }
  cached = v;
}

// ---------------------------------------------------------------------------
__global__ void prep_kernel(const float* __restrict__ x,
                            const float* __restrict__ Wih1, const float* __restrict__ Whh1,
                            const float* __restrict__ bih1, const float* __restrict__ bhh1,
                            const float* __restrict__ Wih2, const float* __restrict__ Whh2,
                            const float* __restrict__ bih2, const float* __restrict__ bhh2,
                            const float* __restrict__ Wih3, const float* __restrict__ Whh3,
                            const float* __restrict__ bih3, const float* __restrict__ bhh3,
                            const float* __restrict__ Wlin, const float* __restrict__ blin,
                            float* __restrict__ ws) {
  int idx = blockIdx.x * 256 + threadIdx.x;
  if (idx < SCAL) {
    int p = idx >> 16;            // plane
    int rem = idx & 65535;
    int k = rem >> 9, g = rem & 511;
    float v;
    switch (p) {
      case 0:  v = Whh1[g * HH + k];         break;
      case 1:  v = Wih2[g * 129 + 1 + k];    break;
      case 2:  v = Whh2[g * HH + k];         break;
      case 3:  v = Wih3[g * 257 + 1 + k];    break;
      case 4:  v = Wih3[g * 257 + 129 + k];  break;
      default: v = Whh3[g * HH + k];         break;
    }
    ws[idx] = v;
  } else if (idx < WLIN) {
    int r = idx - SCAL;
    float v;
    if      (r < 512)  v = Wih1[r];
    else if (r < 1024) v = Wih2[(r - 512) * 129];
    else if (r < 1536) v = Wih3[(r - 1024) * 257];
    else if (r < 2048) v = bih1[r - 1536] + bhh1[r - 1536];
    else if (r < 2560) v = bih2[r - 2048] + bhh2[r - 2048];
    else               v = bih3[r - 2560] + bhh3[r - 2560];
    ws[idx] = v;
  } else if (idx < XT) {
    int j = idx - WLIN;
    ws[idx] = (j < 385) ? Wlin[j] : (j == 385 ? blin[0] : 0.0f);
  } else if (idx < RH1) {
    int j = idx - XT;
    int t = j >> 8, r = j & 255;
    ws[idx] = x[r * TSEQ + t];
  } else if (idx < PREP_TOT) {
    ws[FLAGS + (idx - RH1)] = 0.0f;   // zero flag lines (ws is poisoned)
  }
}

// ---------------------------------------------------------------------------
// Half-K dot: 64 of 128 k-values, 8 rows. acc[a] = sum_k w[k]*hbuf[a][kh*64+k].
__device__ __forceinline__ void dot64(const float* __restrict__ w,
                                      const float* __restrict__ hb,
                                      float acc[8]) {
  #pragma unroll
  for (int k4 = 0; k4 < 16; ++k4) {
    const float w0 = w[4 * k4], w1 = w[4 * k4 + 1];
    const float w2 = w[4 * k4 + 2], w3 = w[4 * k4 + 3];
    #pragma unroll
    for (int a = 0; a < 8; ++a) {
      const float4 h4 = *(const float4*)&hb[a * HH + k4 * 4];
      acc[a] = fmaf(w0, h4.x, fmaf(w1, h4.y, fmaf(w2, h4.z, fmaf(w3, h4.w, acc[a]))));
    }
  }
}

// ---------------------------------------------------------------------------
// Core stage: gates = Whh*h_own (K-split) + [partials or x-term]; act; publish.
// DRH: dword offset of destination h ring.
template <int SSELF, int SWA, int SWB, int NP, int XF, int PB, int PR1, int PR2, int DRH>
__device__ void core_stage(float* __restrict__ wsm, char* SB, int g) {
  const int tid = threadIdx.x;              // [0,1024)
  const int r0 = g * 8;
  float* gs   = (float*)SB;                 // [8][2][512] = 32768 B
  float* hown = (float*)(SB + 32768);       // [8][128] = 4096 B

  unsigned* flagb = (unsigned*)wsm + FLAGS;
  unsigned* Fself = flagb + (size_t)(SSELF * 32 + g) * 32;
  unsigned* Fh    = flagb + (size_t)(6 * 32 + g) * 32;
  unsigned ca = 0, cb = 0, ch = 0;

  // dot role: (col, k-half)
  const int col = tid & 511, kh = tid >> 9;
  float w[64];
  #pragma unroll
  for (int k = 0; k < 64; ++k)
    w[k] = wsm[(size_t)PB * 65536 + (size_t)(kh * 64 + k) * 512 + col];

  // activation role: unit (row, u); gate cols {u,128+u,256+u,384+u}
  const int row = tid >> 7, u = tid & 127;
  float xw4[4], bs4[4];
  if (XF) {
    #pragma unroll
    for (int q = 0; q < 4; ++q) {
      xw4[q] = wsm[SCAL + q * 128 + u];
      bs4[q] = wsm[SCAL + 1536 + q * 128 + u];
    }
  }

  hown[tid & 1023] = 0.f;                   // 8*128 = 1024 = blockDim
  float cst = 0.f;
  __syncthreads();

  for (int t = 0; t < TT; ++t) {
    if (tid == 0) {
      if constexpr (SWA >= 0)
        wait_c(flagb + (size_t)(SWA * 32 + g) * 32, (unsigned)(t + 1), ca);
      if constexpr (SWB >= 0)
        wait_c(flagb + (size_t)(SWB * 32 + g) * 32, (unsigned)(t + 1), cb);
      unsigned ht = (t >= 15) ? (unsigned)(t - 14) : 0u;
      if (XF && t >= TSEQ && (unsigned)t > ht) ht = (unsigned)t;
      if (ht) wait_c(Fh, ht, ch);
    }
    __syncthreads();                 // B1: inputs granted
    const int slot = t & 15;

    // activation-role prefetch: issue ring/x loads early, consume after B2.
    float pa[4], pb[4], xr;
    if constexpr (NP >= 1) {
      #pragma unroll
      for (int q = 0; q < 4; ++q) {
        unsigned uu = __hip_atomic_load(
            (unsigned*)wsm + PR1 + (size_t)(t & 7) * 131072 +
                (size_t)(r0 + row) * 512 + q * 128 + u,
            __ATOMIC_RELAXED, __HIP_MEMORY_SCOPE_AGENT);
        pa[q] = __builtin_bit_cast(float, uu);
      }
    }
    if constexpr (NP == 2) {
      #pragma unroll
      for (int q = 0; q < 4; ++q) {
        unsigned uu = __hip_atomic_load(
            (unsigned*)wsm + PR2 + (size_t)(t & 7) * 131072 +
                (size_t)(r0 + row) * 512 + q * 128 + u,
            __ATOMIC_RELAXED, __HIP_MEMORY_SCOPE_AGENT);
        pb[q] = __builtin_bit_cast(float, uu);
      }
    }
    if (XF) {
      if (t < TSEQ) {
        xr = wsm[XT + (size_t)t * 256 + r0 + row];
      } else {
        unsigned uu = __hip_atomic_load(
            (unsigned*)wsm + RO + (size_t)((t - 1) & 15) * 256 + r0 + row,
            __ATOMIC_RELAXED, __HIP_MEMORY_SCOPE_AGENT);
        xr = __builtin_bit_cast(float, uu);
      }
    }

    // half-K dot on own h
    float acc[8] = {0.f, 0.f, 0.f, 0.f, 0.f, 0.f, 0.f, 0.f};
    dot64(w, hown + kh * 64, acc);
    #pragma unroll
    for (int a = 0; a < 8; ++a) gs[a * 1024 + kh * 512 + col] = acc[a];
    __syncthreads();                 // B2: half-sums visible

    // activation: 1 unit/thread; combine halves + add-terms; publish h
    {
      float gv[4];
      #pragma unroll
      for (int q = 0; q < 4; ++q) {
        const int c0 = q * 128 + u;
        float add;
        if constexpr (NP == 0)      add = fmaf(xw4[q], xr, bs4[q]);
        else if constexpr (NP == 1) add = pa[q];
        else                        add = pa[q] + pb[q];
        gv[q] = gs[row * 1024 + c0] + gs[row * 1024 + 512 + c0] + add;
      }
      const float c = sigmoidf_(gv[1]) * cst + sigmoidf_(gv[0]) * tanhf(gv[2]);
      cst = c;
      const float h = sigmoidf_(gv[3]) * tanhf(c);
      hown[row * HH + u] = h;
      __hip_atomic_store(
          (unsigned*)wsm + DRH + (size_t)slot * 32768 + (size_t)(r0 + row) * 128 + u,
          __builtin_bit_cast(unsigned, h),
          __ATOMIC_RELAXED, __HIP_MEMORY_SCOPE_AGENT);
    }
    __syncthreads();                 // B3: hown visible, stores drained
    if (tid == 0)
      __hip_atomic_fetch_add(Fself, 1u, __ATOMIC_RELAXED, __HIP_MEMORY_SCOPE_AGENT);
  }
}

// ---------------------------------------------------------------------------
// Helper stage: partial = [x-term+bias if XF] + Wpart * h_src(t) (K-split);
// combine halves via LDS; publish to partial ring.
// SC: DIRECT-CONSUMER stage id for the RP anti-dep (re-gated from head).
// Strict need: consumer >= t-7; we wait >= t-6 (margin 1). XF helpers also
// need head >= t for the RO feedback in the tail (t >= TSEQ).
template <int SSELF, int SW, int SC, int XF, int PB, int SI, int SRH64, int DRP>
__device__ void helper_stage(float* __restrict__ wsm, char* SB, int g) {
  const int tid = threadIdx.x;
  const int r0 = g * 8;
  float* ps  = (float*)SB;                  // [8][2][512] = 32768 B
  float* hin = (float*)(SB + 32768);        // [8][128] = 4096 B
  float* xs  = (float*)(SB + 36864);        // [8]

  u64* ws64 = (u64*)wsm;
  unsigned* flagb = (unsigned*)wsm + FLAGS;
  unsigned* Fself = flagb + (size_t)(SSELF * 32 + g) * 32;
  unsigned* Fw    = flagb + (size_t)(SW * 32 + g) * 32;
  unsigned* Fc    = flagb + (size_t)(SC * 32 + g) * 32;
  unsigned* Fhd   = flagb + (size_t)(6 * 32 + g) * 32;
  unsigned cw = 0, cc = 0, chd = 0;

  const int col = tid & 511, kh = tid >> 9;
  float w[64];
  #pragma unroll
  for (int k = 0; k < 64; ++k)
    w[k] = wsm[(size_t)PB * 65536 + (size_t)(kh * 64 + k) * 512 + col];
  const float xwv = XF ? wsm[SCAL + SI * 512 + col] : 0.f;
  const float bsv = XF ? wsm[SCAL + 1536 + SI * 512 + col] : 0.f;
  __syncthreads();

  for (int t = 0; t < TT; ++t) {
    if (tid == 0) {
      wait_c(Fw, (unsigned)(t + 1), cw);
      if (t >= 7) wait_c(Fc, (unsigned)(t - 6), cc);
      if (XF && t >= TSEQ) wait_c(Fhd, (unsigned)t, chd);
    }
    __syncthreads();                 // B1: inputs granted
    const int slot = t & 15;

    if (XF) {
      if (tid < 8) {
        float xv;
        if (t < TSEQ) {
          xv = wsm[XT + (size_t)t * 256 + r0 + tid];
        } else {
          unsigned uu = __hip_atomic_load(
              (unsigned*)wsm + RO + (size_t)((t - 1) & 15) * 256 + r0 + tid,
              __ATOMIC_RELAXED, __HIP_MEMORY_SCOPE_AGENT);
          xv = __builtin_bit_cast(float, uu);
        }
        xs[tid] = xv;
      }
    }
    // stage h_src(t): 512 u64 / first 512 threads
    if (tid < 512) {
      const int a = tid >> 6, up = tid & 63;
      u64 v = __hip_atomic_load(
          ws64 + SRH64 + (size_t)slot * 16384 + (size_t)(r0 + a) * 64 + up,
          __ATOMIC_RELAXED, __HIP_MEMORY_SCOPE_AGENT);
      *(u64*)&hin[a * HH + up * 2] = v;
    }
    __syncthreads();                 // B2: hin (and xs) visible

    float acc[8] = {0.f, 0.f, 0.f, 0.f, 0.f, 0.f, 0.f, 0.f};
    dot64(w, hin + kh * 64, acc);
    #pragma unroll
    for (int a = 0; a < 8; ++a) ps[a * 1024 + kh * 512 + col] = acc[a];
    __syncthreads();                 // B3: half-sums visible

    // combine + publish: 4096 values / 1024 thr = 4 each (same col, rows +2)
    #pragma unroll
    for (int i = 0; i < 4; ++i) {
      const int a = kh + i * 2;             // 0..7
      float v = ps[a * 1024 + col] + ps[a * 1024 + 512 + col];
      if (XF) v += fmaf(xwv, xs[a], bsv);
      __hip_atomic_store(
          (unsigned*)wsm + DRP + (size_t)(t & 7) * 131072 + (size_t)(r0 + a) * 512 + col,
          __builtin_bit_cast(unsigned, v),
          __ATOMIC_RELAXED, __HIP_MEMORY_SCOPE_AGENT);
    }
    __syncthreads();                 // B4: ring stores drained
    if (tid == 0)
      __hip_atomic_fetch_add(Fself, 1u, __ATOMIC_RELAXED, __HIP_MEMORY_SCOPE_AGENT);
  }
}

// ---------------------------------------------------------------------------
__device__ void head_stage(float* __restrict__ wsm, char* SB, int g,
                           float* __restrict__ out) {
  const int tid = threadIdx.x;
  const int r0 = g * 8;
  float* hin  = (float*)SB;                 // [3][8][128] = 12288 B
  float* obuf = (float*)(SB + 12288);       // [8][32]

  u64* ws64 = (u64*)wsm;
  unsigned* flagb = (unsigned*)wsm + FLAGS;
  unsigned* Fself = flagb + (size_t)(6 * 32 + g) * 32;
  unsigned* Fc3   = flagb + (size_t)(5 * 32 + g) * 32;
  unsigned c3c = 0;

  const int row = (tid >> 6) & 7, lane = tid & 63;
  float wlr[6];
  #pragma unroll
  for (int q = 0; q < 6; ++q) wlr[q] = wsm[WLIN + 1 + lane + 64 * q];
  const float wl0 = wsm[WLIN];
  const float blv = wsm[WLIN + 385];
  float xv = wsm[XT + r0 + row];

  for (int t = 0; t < TT; ++t) {
    if (tid == 0) wait_c(Fc3, (unsigned)(t + 1), c3c);
    __syncthreads();                 // B1
    const int slot = t & 15;

    #pragma unroll
    for (int i = 0; i < 2; ++i) {
      const int idx = tid + i * 1024;       // 0..2047, use 0..1535
      if (idx < 1536) {
        const int s = idx >> 9, rem = idx & 511;
        const int a = rem >> 6, up = rem & 63;
        const size_t base = (s == 0) ? (size_t)RH1_64 : (s == 1) ? (size_t)RH2_64 : (size_t)RH3_64;
        u64 v = __hip_atomic_load(
            ws64 + base + (size_t)slot * 16384 + (size_t)(r0 + a) * 64 + up,
            __ATOMIC_RELAXED, __HIP_MEMORY_SCOPE_AGENT);
        *(u64*)&hin[(s * 8 + a) * HH + up * 2] = v;
      }
    }
    __syncthreads();                 // B2

    if (tid < 512) {
      float s = 0.f;
      #pragma unroll
      for (int q = 0; q < 6; ++q) {
        const int j = lane + 64 * q;        // 0..383
        const int si = j >> 7, uu = j & 127;
        s = fmaf(wlr[q], hin[(si * 8 + row) * HH + uu], s);
      }
      #pragma unroll
      for (int off = 32; off > 0; off >>= 1) s += __shfl_down(s, off, 64);
      if (lane == 0) {
        const float o = s + fmaf(wl0, xv, blv);
        obuf[row * 32 + (t & 31)] = o;
        __hip_atomic_store((unsigned*)wsm + RO + (size_t)slot * 256 + r0 + row,
                           __builtin_bit_cast(unsigned, o),
                           __ATOMIC_RELAXED, __HIP_MEMORY_SCOPE_AGENT);
        xv = (t + 1 < TSEQ) ? wsm[XT + (size_t)(t + 1) * 256 + r0 + row] : o;
      }
    }
    __syncthreads();                 // B3: o-store + obuf drained
    if (tid == 0)
      __hip_atomic_fetch_add(Fself, 1u, __ATOMIC_RELAXED, __HIP_MEMORY_SCOPE_AGENT);

    if ((t & 31) == 31) {
      const int tb = t - 31;
      if (tid < 256) {
        const int a = tid >> 5, m = tid & 31;
        out[(size_t)(r0 + a) * TT + tb + m] = obuf[a * 32 + m];
      }
    }
  }
}

// ---------------------------------------------------------------------------
__global__ __launch_bounds__(1024)
void lstm_kernel(float* __restrict__ wsm, float* __restrict__ out) {
  __shared__ __align__(16) char SB[36992];
  const int s = blockIdx.x >> 5, g = blockIdx.x & 31;
  switch (s) {
    case 0: core_stage<0, -1, -1, 0, 1, 0, 0, 0, RH1>(wsm, SB, g); break;
    case 1: helper_stage<1, 0, 2, 1, 1, 1, RH1_64, RP2>(wsm, SB, g); break;
    case 2: core_stage<2, 1, -1, 1, 0, 2, RP2, 0, RH2>(wsm, SB, g); break;
    case 3: helper_stage<3, 0, 5, 1, 3, 2, RH1_64, RP3A>(wsm, SB, g); break;
    case 4: helper_stage<4, 2, 5, 0, 4, 0, RH2_64, RP3B>(wsm, SB, g); break;
    case 5: core_stage<5, 3, 4, 2, 0, 5, RP3A, RP3B, RH3>(wsm, SB, g); break;
    default: head_stage(wsm, SB, g, out); break;
  }
}

// ---------------------------------------------------------------------------
extern "C" void kernel_launch(void* const* d_in, const int* in_sizes, int n_in,
                              void* d_out, int out_size, void* d_ws, size_t ws_size,
                              hipStream_t stream) {
  const float* x    = (const float*)d_in[0];
  const float* Wih1 = (const float*)d_in[1];
  const float* Whh1 = (const float*)d_in[2];
  const float* bih1 = (const float*)d_in[3];
  const float* bhh1 = (const float*)d_in[4];
  const float* Wih2 = (const float*)d_in[5];
  const float* Whh2 = (const float*)d_in[6];
  const float* bih2 = (const float*)d_in[7];
  const float* bhh2 = (const float*)d_in[8];
  const float* Wih3 = (const float*)d_in[9];
  const float* Whh3 = (const float*)d_in[10];
  const float* bih3 = (const float*)d_in[11];
  const float* bhh3 = (const float*)d_in[12];
  const float* Wlin = (const float*)d_in[13];
  const float* blin = (const float*)d_in[14];
  float* ws  = (float*)d_ws;
  float* out = (float*)d_out;

  prep_kernel<<<PREP_TOT / 256, 256, 0, stream>>>(
      x, Wih1, Whh1, bih1, bhh1, Wih2, Whh2, bih2, bhh2,
      Wih3, Whh3, bih3, bhh3, Wlin, blin, ws);
  lstm_kernel<<<224, THR, 0, stream>>>(ws, out);
}

// Round 18
// 6805.746 us; speedup vs baseline: 4.4015x; 1.2203x over previous
//
#include <hip/hip_runtime.h>
#include <math.h>

// DenseLSTMForecast: B=256, T=1024, H=128, FUTURE=32.
// R14: G=2 x K-quarter dot (1024 LDS b128/CU/step) at 4 waves/SIMD.
// R13 post-mortem (8305us): consumer-gating ~null (+2%). Re-fit:
//   R7  2048 reads 2w -> 19.3k cy/step
//   R11 2048 reads 4w -> 19.3k  (wave-insensitive at fixed traffic!)
//   R10 1024 reads 1w -> 38.4k  (latency regime, confounded)
// Wave-insensitivity at fixed LDS traffic = shared-pipe throughput bound:
// 19.3k/2048 ~ 9.4 cy per broadcast ds_read_b128 (~known b128 rate).
// R10's "falsification" changed TWO variables (traffic AND waves); the
// missing quadrant (1024 reads, >=2w) is what R14 measures.
// Change vs R13 (verified): dot split by (column-pair, k-quarter):
// thread owns cols {c,c+256} x k-range [kq*32,kq*32+32): w0[32],w1[32].
// Each broadcast h4 feeds 8 FMAs (2 gates x 4 k) -> per-CU LDS reads
// halved to 1024/step. Partials gs/ps[8][4][512] (64KB); activation and
// helper-combine sum 4 partials. ~110 regs/thread fits 16-wave residency.
// Rings/flags/prep/sync byte-identical to R13 (tid0 poll + B1 grant,
// consumer-gated helper anti-deps, head-gated core h-rings).
// Geometry: 1024-thr blocks, 32 groups x 8 rows, 224 WGs, 7 stages:
//   s0 c1-core   : g1 = xw1*x+b1 + Whh1*h1           -> RH1 ring
//   s1 c2-helper : p2 = xw2*x+b2 + Wih2[:,1:]*h1(t)  -> RP2 ring
//   s2 c2-core   : g2 = p2 + Whh2*h2                 -> RH2 ring
//   s3 c3-helperA: pA = xw3*x+b3 + Wih3[:,1:129]*h1  -> RP3A ring
//   s4 c3-helperB: pB = Wih3[:,129:257]*h2           -> RP3B ring
//   s5 c3-core   : g3 = pA+pB + Whh3*h3              -> RH3 ring
//   s6 head      : o = Wlin.[x,h1,h2,h3]+b           -> RO ring + out
// Prediction: pipe-bound -> 4800-5800us, VALU 50-60%; null (~19k cy) ->
// LDS-pipe theory dead (both quadrants measured) -> stage fusion next.

#define TSEQ 1024
#define HH   128
#define TT   1056
#define THR  1024

// ---- ws dword offsets (identical to R7) ----
#define PLANES   0                 // 6 planes x [128 k][512 g] fp32
#define SCAL     393216            // xw1,xw2,xw3,bs1,bs2,bs3 (512 each)
#define WLIN     396288            // Wlin[0..384], [385]=b_lin, pad 512
#define XT       396800            // x transposed [1024][256]
#define RH1      658944            // h rings: [16][256][128] fp32
#define RH2      1183232
#define RH3      1707520
#define RO       2231808           // o ring [16][256] fp32
#define RP2      2235904           // partial rings: [8][256][512] fp32
#define RP3A     3284480
#define RP3B     4333056
#define FLAGS    5381632           // 224 x 32-dword lines
#define PREP_TOT 666112            // 658944 + 7168 (flags zeroing)

#define RH1_64 (RH1/2)
#define RH2_64 (RH2/2)
#define RH3_64 (RH3/2)

typedef unsigned long long u64;

__device__ __forceinline__ float sigmoidf_(float v) {
  return 1.0f / (1.0f + expf(-v));
}

__device__ __forceinline__ void wait_c(unsigned* p, unsigned tgt, unsigned& cached) {
  if (cached >= tgt) return;
  unsigned v = __hip_atomic_load(p, __ATOMIC_ACQUIRE, __HIP_MEMORY_SCOPE_AGENT);
  while (v < tgt) {
    __builtin_amdgcn_s_sleep(1);
    v = __hip_atomic_load(p, __ATOMIC_ACQUIRE, __HIP_MEMORY_SCOPE_AGENT);
  }
  cached = v;
}

// ---------------------------------------------------------------------------
__global__ void prep_kernel(const float* __restrict__ x,
                            const float* __restrict__ Wih1, const float* __restrict__ Whh1,
                            const float* __restrict__ bih1, const float* __restrict__ bhh1,
                            const float* __restrict__ Wih2, const float* __restrict__ Whh2,
                            const float* __restrict__ bih2, const float* __restrict__ bhh2,
                            const float* __restrict__ Wih3, const float* __restrict__ Whh3,
                            const float* __restrict__ bih3, const float* __restrict__ bhh3,
                            const float* __restrict__ Wlin, const float* __restrict__ blin,
                            float* __restrict__ ws) {
  int idx = blockIdx.x * 256 + threadIdx.x;
  if (idx < SCAL) {
    int p = idx >> 16;            // plane
    int rem = idx & 65535;
    int k = rem >> 9, g = rem & 511;
    float v;
    switch (p) {
      case 0:  v = Whh1[g * HH + k];         break;
      case 1:  v = Wih2[g * 129 + 1 + k];    break;
      case 2:  v = Whh2[g * HH + k];         break;
      case 3:  v = Wih3[g * 257 + 1 + k];    break;
      case 4:  v = Wih3[g * 257 + 129 + k];  break;
      default: v = Whh3[g * HH + k];         break;
    }
    ws[idx] = v;
  } else if (idx < WLIN) {
    int r = idx - SCAL;
    float v;
    if      (r < 512)  v = Wih1[r];
    else if (r < 1024) v = Wih2[(r - 512) * 129];
    else if (r < 1536) v = Wih3[(r - 1024) * 257];
    else if (r < 2048) v = bih1[r - 1536] + bhh1[r - 1536];
    else if (r < 2560) v = bih2[r - 2048] + bhh2[r - 2048];
    else               v = bih3[r - 2560] + bhh3[r - 2560];
    ws[idx] = v;
  } else if (idx < XT) {
    int j = idx - WLIN;
    ws[idx] = (j < 385) ? Wlin[j] : (j == 385 ? blin[0] : 0.0f);
  } else if (idx < RH1) {
    int j = idx - XT;
    int t = j >> 8, r = j & 255;
    ws[idx] = x[r * TSEQ + t];
  } else if (idx < PREP_TOT) {
    ws[FLAGS + (idx - RH1)] = 0.0f;   // zero flag lines (ws is poisoned)
  }
}

// ---------------------------------------------------------------------------
// Quarter-K G=2 dot: 32 k-values, 8 rows, 2 gate cols.
// hb pre-offset by kq*32. One broadcast h4 read feeds 8 FMAs.
__device__ __forceinline__ void dot32_g2(const float* __restrict__ w0,
                                         const float* __restrict__ w1,
                                         const float* __restrict__ hb,
                                         float acc0[8], float acc1[8]) {
  #pragma unroll
  for (int k4 = 0; k4 < 8; ++k4) {
    const float a0 = w0[4 * k4], a1 = w0[4 * k4 + 1];
    const float a2 = w0[4 * k4 + 2], a3 = w0[4 * k4 + 3];
    const float b0 = w1[4 * k4], b1 = w1[4 * k4 + 1];
    const float b2 = w1[4 * k4 + 2], b3 = w1[4 * k4 + 3];
    #pragma unroll
    for (int a = 0; a < 8; ++a) {
      const float4 h4 = *(const float4*)&hb[a * HH + k4 * 4];
      acc0[a] = fmaf(a0, h4.x, fmaf(a1, h4.y, fmaf(a2, h4.z, fmaf(a3, h4.w, acc0[a]))));
      acc1[a] = fmaf(b0, h4.x, fmaf(b1, h4.y, fmaf(b2, h4.z, fmaf(b3, h4.w, acc1[a]))));
    }
  }
}

// ---------------------------------------------------------------------------
// Core stage: gates = Whh*h_own (G=2 x K/4 split) + [partials or x-term].
// DRH: dword offset of destination h ring.
template <int SSELF, int SWA, int SWB, int NP, int XF, int PB, int PR1, int PR2, int DRH>
__device__ void core_stage(float* __restrict__ wsm, char* SB, int g) {
  const int tid = threadIdx.x;              // [0,1024)
  const int r0 = g * 8;
  float* gs   = (float*)SB;                 // [8][4][512] = 65536 B
  float* hown = (float*)(SB + 65536);       // [8][128] = 4096 B

  unsigned* flagb = (unsigned*)wsm + FLAGS;
  unsigned* Fself = flagb + (size_t)(SSELF * 32 + g) * 32;
  unsigned* Fh    = flagb + (size_t)(6 * 32 + g) * 32;
  unsigned ca = 0, cb = 0, ch = 0;

  // dot role: (column-pair, k-quarter)
  const int col = tid & 255, kq = tid >> 8;
  float w0[32], w1[32];
  #pragma unroll
  for (int k = 0; k < 32; ++k) {
    w0[k] = wsm[(size_t)PB * 65536 + (size_t)(kq * 32 + k) * 512 + col];
    w1[k] = wsm[(size_t)PB * 65536 + (size_t)(kq * 32 + k) * 512 + col + 256];
  }

  // activation role: unit (row, u); gate cols {u,128+u,256+u,384+u}
  const int row = tid >> 7, u = tid & 127;
  float xw4[4], bs4[4];
  if (XF) {
    #pragma unroll
    for (int q = 0; q < 4; ++q) {
      xw4[q] = wsm[SCAL + q * 128 + u];
      bs4[q] = wsm[SCAL + 1536 + q * 128 + u];
    }
  }

  hown[tid & 1023] = 0.f;                   // 8*128 = 1024 = blockDim
  float cst = 0.f;
  __syncthreads();

  for (int t = 0; t < TT; ++t) {
    if (tid == 0) {
      if constexpr (SWA >= 0)
        wait_c(flagb + (size_t)(SWA * 32 + g) * 32, (unsigned)(t + 1), ca);
      if constexpr (SWB >= 0)
        wait_c(flagb + (size_t)(SWB * 32 + g) * 32, (unsigned)(t + 1), cb);
      unsigned ht = (t >= 15) ? (unsigned)(t - 14) : 0u;
      if (XF && t >= TSEQ && (unsigned)t > ht) ht = (unsigned)t;
      if (ht) wait_c(Fh, ht, ch);
    }
    __syncthreads();                 // B1: inputs granted
    const int slot = t & 15;

    // activation-role prefetch: issue ring/x loads early, consume after B2.
    float pa[4], pb[4], xr;
    if constexpr (NP >= 1) {
      #pragma unroll
      for (int q = 0; q < 4; ++q) {
        unsigned uu = __hip_atomic_load(
            (unsigned*)wsm + PR1 + (size_t)(t & 7) * 131072 +
                (size_t)(r0 + row) * 512 + q * 128 + u,
            __ATOMIC_RELAXED, __HIP_MEMORY_SCOPE_AGENT);
        pa[q] = __builtin_bit_cast(float, uu);
      }
    }
    if constexpr (NP == 2) {
      #pragma unroll
      for (int q = 0; q < 4; ++q) {
        unsigned uu = __hip_atomic_load(
            (unsigned*)wsm + PR2 + (size_t)(t & 7) * 131072 +
                (size_t)(r0 + row) * 512 + q * 128 + u,
            __ATOMIC_RELAXED, __HIP_MEMORY_SCOPE_AGENT);
        pb[q] = __builtin_bit_cast(float, uu);
      }
    }
    if (XF) {
      if (t < TSEQ) {
        xr = wsm[XT + (size_t)t * 256 + r0 + row];
      } else {
        unsigned uu = __hip_atomic_load(
            (unsigned*)wsm + RO + (size_t)((t - 1) & 15) * 256 + r0 + row,
            __ATOMIC_RELAXED, __HIP_MEMORY_SCOPE_AGENT);
        xr = __builtin_bit_cast(float, uu);
      }
    }

    // quarter-K G=2 dot on own h
    float acc0[8] = {0.f, 0.f, 0.f, 0.f, 0.f, 0.f, 0.f, 0.f};
    float acc1[8] = {0.f, 0.f, 0.f, 0.f, 0.f, 0.f, 0.f, 0.f};
    dot32_g2(w0, w1, hown + kq * 32, acc0, acc1);
    #pragma unroll
    for (int a = 0; a < 8; ++a) {
      gs[a * 2048 + kq * 512 + col]       = acc0[a];
      gs[a * 2048 + kq * 512 + col + 256] = acc1[a];
    }
    __syncthreads();                 // B2: quarter-sums visible

    // activation: 1 unit/thread; combine 4 partials + add-terms; publish h
    {
      float gv[4];
      #pragma unroll
      for (int q = 0; q < 4; ++q) {
        const int c0 = q * 128 + u;
        float add;
        if constexpr (NP == 0)      add = fmaf(xw4[q], xr, bs4[q]);
        else if constexpr (NP == 1) add = pa[q];
        else                        add = pa[q] + pb[q];
        float s = add;
        #pragma unroll
        for (int p = 0; p < 4; ++p) s += gs[row * 2048 + p * 512 + c0];
        gv[q] = s;
      }
      const float c = sigmoidf_(gv[1]) * cst + sigmoidf_(gv[0]) * tanhf(gv[2]);
      cst = c;
      const float h = sigmoidf_(gv[3]) * tanhf(c);
      hown[row * HH + u] = h;
      __hip_atomic_store(
          (unsigned*)wsm + DRH + (size_t)slot * 32768 + (size_t)(r0 + row) * 128 + u,
          __builtin_bit_cast(unsigned, h),
          __ATOMIC_RELAXED, __HIP_MEMORY_SCOPE_AGENT);
    }
    __syncthreads();                 // B3: hown visible, stores drained
    if (tid == 0)
      __hip_atomic_fetch_add(Fself, 1u, __ATOMIC_RELAXED, __HIP_MEMORY_SCOPE_AGENT);
  }
}

// ---------------------------------------------------------------------------
// Helper stage: partial = [x-term+bias if XF] + Wpart * h_src(t) (G=2 x K/4);
// combine 4 partials via LDS; publish to partial ring.
// SC: DIRECT-CONSUMER stage id for the RP anti-dep (>= t-6, strict t-7).
template <int SSELF, int SW, int SC, int XF, int PB, int SI, int SRH64, int DRP>
__device__ void helper_stage(float* __restrict__ wsm, char* SB, int g) {
  const int tid = threadIdx.x;
  const int r0 = g * 8;
  float* ps  = (float*)SB;                  // [8][4][512] = 65536 B
  float* hin = (float*)(SB + 65536);        // [8][128] = 4096 B
  float* xs  = (float*)(SB + 69632);        // [8]

  u64* ws64 = (u64*)wsm;
  unsigned* flagb = (unsigned*)wsm + FLAGS;
  unsigned* Fself = flagb + (size_t)(SSELF * 32 + g) * 32;
  unsigned* Fw    = flagb + (size_t)(SW * 32 + g) * 32;
  unsigned* Fc    = flagb + (size_t)(SC * 32 + g) * 32;
  unsigned* Fhd   = flagb + (size_t)(6 * 32 + g) * 32;
  unsigned cw = 0, cc = 0, chd = 0;

  const int col = tid & 255, kq = tid >> 8;
  float w0[32], w1[32];
  #pragma unroll
  for (int k = 0; k < 32; ++k) {
    w0[k] = wsm[(size_t)PB * 65536 + (size_t)(kq * 32 + k) * 512 + col];
    w1[k] = wsm[(size_t)PB * 65536 + (size_t)(kq * 32 + k) * 512 + col + 256];
  }
  const float xwv0 = XF ? wsm[SCAL + SI * 512 + col] : 0.f;
  const float xwv1 = XF ? wsm[SCAL + SI * 512 + col + 256] : 0.f;
  const float bsv0 = XF ? wsm[SCAL + 1536 + SI * 512 + col] : 0.f;
  const float bsv1 = XF ? wsm[SCAL + 1536 + SI * 512 + col + 256] : 0.f;
  __syncthreads();

  for (int t = 0; t < TT; ++t) {
    if (tid == 0) {
      wait_c(Fw, (unsigned)(t + 1), cw);
      if (t >= 7) wait_c(Fc, (unsigned)(t - 6), cc);
      if (XF && t >= TSEQ) wait_c(Fhd, (unsigned)t, chd);
    }
    __syncthreads();                 // B1: inputs granted
    const int slot = t & 15;

    if (XF) {
      if (tid < 8) {
        float xv;
        if (t < TSEQ) {
          xv = wsm[XT + (size_t)t * 256 + r0 + tid];
        } else {
          unsigned uu = __hip_atomic_load(
              (unsigned*)wsm + RO + (size_t)((t - 1) & 15) * 256 + r0 + tid,
              __ATOMIC_RELAXED, __HIP_MEMORY_SCOPE_AGENT);
          xv = __builtin_bit_cast(float, uu);
        }
        xs[tid] = xv;
      }
    }
    // stage h_src(t): 512 u64 / first 512 threads
    if (tid < 512) {
      const int a = tid >> 6, up = tid & 63;
      u64 v = __hip_atomic_load(
          ws64 + SRH64 + (size_t)slot * 16384 + (size_t)(r0 + a) * 64 + up,
          __ATOMIC_RELAXED, __HIP_MEMORY_SCOPE_AGENT);
      *(u64*)&hin[a * HH + up * 2] = v;
    }
    __syncthreads();                 // B2: hin (and xs) visible

    float acc0[8] = {0.f, 0.f, 0.f, 0.f, 0.f, 0.f, 0.f, 0.f};
    float acc1[8] = {0.f, 0.f, 0.f, 0.f, 0.f, 0.f, 0.f, 0.f};
    dot32_g2(w0, w1, hin + kq * 32, acc0, acc1);
    #pragma unroll
    for (int a = 0; a < 8; ++a) {
      ps[a * 2048 + kq * 512 + col]       = acc0[a];
      ps[a * 2048 + kq * 512 + col + 256] = acc1[a];
    }
    __syncthreads();                 // B3: quarter-sums visible

    // combine + publish: rows {2kq,2kq+1} x cols {col,col+256} = 4/thread
    #pragma unroll
    for (int i = 0; i < 2; ++i) {
      const int a = 2 * kq + i;
      float v0 = XF ? fmaf(xwv0, xs[a], bsv0) : 0.f;
      float v1 = XF ? fmaf(xwv1, xs[a], bsv1) : 0.f;
      #pragma unroll
      for (int p = 0; p < 4; ++p) {
        v0 += ps[a * 2048 + p * 512 + col];
        v1 += ps[a * 2048 + p * 512 + col + 256];
      }
      __hip_atomic_store(
          (unsigned*)wsm + DRP + (size_t)(t & 7) * 131072 + (size_t)(r0 + a) * 512 + col,
          __builtin_bit_cast(unsigned, v0),
          __ATOMIC_RELAXED, __HIP_MEMORY_SCOPE_AGENT);
      __hip_atomic_store(
          (unsigned*)wsm + DRP + (size_t)(t & 7) * 131072 + (size_t)(r0 + a) * 512 + col + 256,
          __builtin_bit_cast(unsigned, v1),
          __ATOMIC_RELAXED, __HIP_MEMORY_SCOPE_AGENT);
    }
    __syncthreads();                 // B4: ring stores drained
    if (tid == 0)
      __hip_atomic_fetch_add(Fself, 1u, __ATOMIC_RELAXED, __HIP_MEMORY_SCOPE_AGENT);
  }
}

// ---------------------------------------------------------------------------
__device__ void head_stage(float* __restrict__ wsm, char* SB, int g,
                           float* __restrict__ out) {
  const int tid = threadIdx.x;
  const int r0 = g * 8;
  float* hin  = (float*)SB;                 // [3][8][128] = 12288 B
  float* obuf = (float*)(SB + 12288);       // [8][32]

  u64* ws64 = (u64*)wsm;
  unsigned* flagb = (unsigned*)wsm + FLAGS;
  unsigned* Fself = flagb + (size_t)(6 * 32 + g) * 32;
  unsigned* Fc3   = flagb + (size_t)(5 * 32 + g) * 32;
  unsigned c3c = 0;

  const int row = (tid >> 6) & 7, lane = tid & 63;
  float wlr[6];
  #pragma unroll
  for (int q = 0; q < 6; ++q) wlr[q] = wsm[WLIN + 1 + lane + 64 * q];
  const float wl0 = wsm[WLIN];
  const float blv = wsm[WLIN + 385];
  float xv = wsm[XT + r0 + row];

  for (int t = 0; t < TT; ++t) {
    if (tid == 0) wait_c(Fc3, (unsigned)(t + 1), c3c);
    __syncthreads();                 // B1
    const int slot = t & 15;

    #pragma unroll
    for (int i = 0; i < 2; ++i) {
      const int idx = tid + i * 1024;       // 0..2047, use 0..1535
      if (idx < 1536) {
        const int s = idx >> 9, rem = idx & 511;
        const int a = rem >> 6, up = rem & 63;
        const size_t base = (s == 0) ? (size_t)RH1_64 : (s == 1) ? (size_t)RH2_64 : (size_t)RH3_64;
        u64 v = __hip_atomic_load(
            ws64 + base + (size_t)slot * 16384 + (size_t)(r0 + a) * 64 + up,
            __ATOMIC_RELAXED, __HIP_MEMORY_SCOPE_AGENT);
        *(u64*)&hin[(s * 8 + a) * HH + up * 2] = v;
      }
    }
    __syncthreads();                 // B2

    if (tid < 512) {
      float s = 0.f;
      #pragma unroll
      for (int q = 0; q < 6; ++q) {
        const int j = lane + 64 * q;        // 0..383
        const int si = j >> 7, uu = j & 127;
        s = fmaf(wlr[q], hin[(si * 8 + row) * HH + uu], s);
      }
      #pragma unroll
      for (int off = 32; off > 0; off >>= 1) s += __shfl_down(s, off, 64);
      if (lane == 0) {
        const float o = s + fmaf(wl0, xv, blv);
        obuf[row * 32 + (t & 31)] = o;
        __hip_atomic_store((unsigned*)wsm + RO + (size_t)slot * 256 + r0 + row,
                           __builtin_bit_cast(unsigned, o),
                           __ATOMIC_RELAXED, __HIP_MEMORY_SCOPE_AGENT);
        xv = (t + 1 < TSEQ) ? wsm[XT + (size_t)(t + 1) * 256 + r0 + row] : o;
      }
    }
    __syncthreads();                 // B3: o-store + obuf drained
    if (tid == 0)
      __hip_atomic_fetch_add(Fself, 1u, __ATOMIC_RELAXED, __HIP_MEMORY_SCOPE_AGENT);

    if ((t & 31) == 31) {
      const int tb = t - 31;
      if (tid < 256) {
        const int a = tid >> 5, m = tid & 31;
        out[(size_t)(r0 + a) * TT + tb + m] = obuf[a * 32 + m];
      }
    }
  }
}

// ---------------------------------------------------------------------------
__global__ __launch_bounds__(1024)
void lstm_kernel(float* __restrict__ wsm, float* __restrict__ out) {
  __shared__ __align__(16) char SB[69664];
  const int s = blockIdx.x >> 5, g = blockIdx.x & 31;
  switch (s) {
    case 0: core_stage<0, -1, -1, 0, 1, 0, 0, 0, RH1>(wsm, SB, g); break;
    case 1: helper_stage<1, 0, 2, 1, 1, 1, RH1_64, RP2>(wsm, SB, g); break;
    case 2: core_stage<2, 1, -1, 1, 0, 2, RP2, 0, RH2>(wsm, SB, g); break;
    case 3: helper_stage<3, 0, 5, 1, 3, 2, RH1_64, RP3A>(wsm, SB, g); break;
    case 4: helper_stage<4, 2, 5, 0, 4, 0, RH2_64, RP3B>(wsm, SB, g); break;
    case 5: core_stage<5, 3, 4, 2, 0, 5, RP3A, RP3B, RH3>(wsm, SB, g); break;
    default: head_stage(wsm, SB, g, out); break;
  }
}

// ---------------------------------------------------------------------------
extern "C" void kernel_launch(void* const* d_in, const int* in_sizes, int n_in,
                              void* d_out, int out_size, void* d_ws, size_t ws_size,
                              hipStream_t stream) {
  const float* x    = (const float*)d_in[0];
  const float* Wih1 = (const float*)d_in[1];
  const float* Whh1 = (const float*)d_in[2];
  const float* bih1 = (const float*)d_in[3];
  const float* bhh1 = (const float*)d_in[4];
  const float* Wih2 = (const float*)d_in[5];
  const float* Whh2 = (const float*)d_in[6];
  const float* bih2 = (const float*)d_in[7];
  const float* bhh2 = (const float*)d_in[8];
  const float* Wih3 = (const float*)d_in[9];
  const float* Whh3 = (const float*)d_in[10];
  const float* bih3 = (const float*)d_in[11];
  const float* bhh3 = (const float*)d_in[12];
  const float* Wlin = (const float*)d_in[13];
  const float* blin = (const float*)d_in[14];
  float* ws  = (float*)d_ws;
  float* out = (float*)d_out;

  prep_kernel<<<PREP_TOT / 256, 256, 0, stream>>>(
      x, Wih1, Whh1, bih1, bhh1, Wih2, Whh2, bih2, bhh2,
      Wih3, Whh3, bih3, bhh3, Wlin, blin, ws);
  lstm_kernel<<<224, THR, 0, stream>>>(ws, out);
}

// Round 20
// 6332.920 us; speedup vs baseline: 4.7302x; 1.0747x over previous
//
#include <hip/hip_runtime.h>
#include <math.h>

// DenseLSTMForecast: B=256, T=1024, H=128, FUTURE=32.
// R15 (2nd submit; round 19 hit GPUAcquisitionTimeout, never measured).
// R15: G=4 dot with gate-contiguous (permuted) partials -> 512 b128/CU/step.
// R14 post-mortem (6806us, VALU 46%): LDS-pipe model CONFIRMED — halving
// b128 reads (2048->1024) cut step 19.3k->15.5k cy. Accounting: 1024 b128
// ~9.2k + ~530 b32 partial traffic ~3k + overlap/barriers = 15.5k.
// R15 halves reads again WITHOUT b32 bloat: each thread owns the 4 GATES
// of one unit (cols {u,128+u,256+u,384+u}) x K/8 -> one broadcast h4 read
// feeds 16 FMAs. Partials stored PERMUTED gs[row][kq][4u+q] so stores are
// b128 and combine+activation FUSE: thread (row,u) reads 8 contiguous
// b128, sums 4 gates, activates. No gates buffer, no extra barrier.
// RP rings switch to permuted column order (4u+q) — helper-combine
// publishes and core-combine reads consistently (rings internal-only);
// ring add-terms become 2 contiguous u64 loads. RH/RO rings unchanged.
// Per-CU LDS/step: 512 read + 128 store + 128 combine b128 ~ 7k cy
// (vs 12.2k in R14). Per-row acc-then-store keeps acc live=4 (~90-120
// regs; 16-wave residency). Sync = verified R13 (tid0 poll + B1 grant,
// consumer-gated helper anti-deps, head-gated core h-rings).
// Geometry: 1024-thr blocks, 32 groups x 8 rows, 224 WGs, 7 stages:
//   s0 c1-core   : g1 = xw1*x+b1 + Whh1*h1           -> RH1 ring
//   s1 c2-helper : p2 = xw2*x+b2 + Wih2[:,1:]*h1(t)  -> RP2 ring (perm)
//   s2 c2-core   : g2 = p2 + Whh2*h2                 -> RH2 ring
//   s3 c3-helperA: pA = xw3*x+b3 + Wih3[:,1:129]*h1  -> RP3A ring (perm)
//   s4 c3-helperB: pB = Wih3[:,129:257]*h2           -> RP3B ring (perm)
//   s5 c3-core   : g3 = pA+pB + Whh3*h3              -> RH3 ring
//   s6 head      : o = Wlin.[x,h1,h2,h3]+b           -> RO ring + out
// Prediction: step -> 10.5-12k cy (4400-5300us), VALU 55-65%, LDS ~135KB,
// VGPR 90-128 no scratch. Null (>=6.3ms): LDS overlapped; barrier/flag
// serial floor -> fuse stages next. Launch-fail => regs>128: 512-thr
// fallback next round.

#define TSEQ 1024
#define HH   128
#define TT   1056
#define THR  1024

// ---- ws dword offsets (identical to R7) ----
#define PLANES   0                 // 6 planes x [128 k][512 g] fp32
#define SCAL     393216            // xw1,xw2,xw3,bs1,bs2,bs3 (512 each)
#define WLIN     396288            // Wlin[0..384], [385]=b_lin, pad 512
#define XT       396800            // x transposed [1024][256]
#define RH1      658944            // h rings: [16][256][128] fp32
#define RH2      1183232
#define RH3      1707520
#define RO       2231808           // o ring [16][256] fp32
#define RP2      2235904           // partial rings: [8][256][512] fp32 (PERMUTED cols)
#define RP3A     3284480
#define RP3B     4333056
#define FLAGS    5381632           // 224 x 32-dword lines
#define PREP_TOT 666112            // 658944 + 7168 (flags zeroing)

#define RH1_64 (RH1/2)
#define RH2_64 (RH2/2)
#define RH3_64 (RH3/2)

typedef unsigned long long u64;

__device__ __forceinline__ float sigmoidf_(float v) {
  return 1.0f / (1.0f + expf(-v));
}

__device__ __forceinline__ void wait_c(unsigned* p, unsigned tgt, unsigned& cached) {
  if (cached >= tgt) return;
  unsigned v = __hip_atomic_load(p, __ATOMIC_ACQUIRE, __HIP_MEMORY_SCOPE_AGENT);
  while (v < tgt) {
    __builtin_amdgcn_s_sleep(1);
    v = __hip_atomic_load(p, __ATOMIC_ACQUIRE, __HIP_MEMORY_SCOPE_AGENT);
  }
  cached = v;
}

// ---------------------------------------------------------------------------
__global__ void prep_kernel(const float* __restrict__ x,
                            const float* __restrict__ Wih1, const float* __restrict__ Whh1,
                            const float* __restrict__ bih1, const float* __restrict__ bhh1,
                            const float* __restrict__ Wih2, const float* __restrict__ Whh2,
                            const float* __restrict__ bih2, const float* __restrict__ bhh2,
                            const float* __restrict__ Wih3, const float* __restrict__ Whh3,
                            const float* __restrict__ bih3, const float* __restrict__ bhh3,
                            const float* __restrict__ Wlin, const float* __restrict__ blin,
                            float* __restrict__ ws) {
  int idx = blockIdx.x * 256 + threadIdx.x;
  if (idx < SCAL) {
    int p = idx >> 16;            // plane
    int rem = idx & 65535;
    int k = rem >> 9, g = rem & 511;
    float v;
    switch (p) {
      case 0:  v = Whh1[g * HH + k];         break;
      case 1:  v = Wih2[g * 129 + 1 + k];    break;
      case 2:  v = Whh2[g * HH + k];         break;
      case 3:  v = Wih3[g * 257 + 1 + k];    break;
      case 4:  v = Wih3[g * 257 + 129 + k];  break;
      default: v = Whh3[g * HH + k];         break;
    }
    ws[idx] = v;
  } else if (idx < WLIN) {
    int r = idx - SCAL;
    float v;
    if      (r < 512)  v = Wih1[r];
    else if (r < 1024) v = Wih2[(r - 512) * 129];
    else if (r < 1536) v = Wih3[(r - 1024) * 257];
    else if (r < 2048) v = bih1[r - 1536] + bhh1[r - 1536];
    else if (r < 2560) v = bih2[r - 2048] + bhh2[r - 2048];
    else               v = bih3[r - 2560] + bhh3[r - 2560];
    ws[idx] = v;
  } else if (idx < XT) {
    int j = idx - WLIN;
    ws[idx] = (j < 385) ? Wlin[j] : (j == 385 ? blin[0] : 0.0f);
  } else if (idx < RH1) {
    int j = idx - XT;
    int t = j >> 8, r = j & 255;
    ws[idx] = x[r * TSEQ + t];
  } else if (idx < PREP_TOT) {
    ws[FLAGS + (idx - RH1)] = 0.0f;   // zero flag lines (ws is poisoned)
  }
}

// ---------------------------------------------------------------------------
// G=4 K/8 dot for one row: 16 k-values, 4 gates of unit ud.
// hb pre-offset to the row base + kq*16. Returns acc as float4 (gate order).
__device__ __forceinline__ float4 dot16_g4(const float w[4][16],
                                           const float* __restrict__ hb) {
  float a0 = 0.f, a1 = 0.f, a2 = 0.f, a3 = 0.f;
  #pragma unroll
  for (int k4 = 0; k4 < 4; ++k4) {
    const float4 h4 = *(const float4*)&hb[k4 * 4];
    #pragma unroll
    for (int j = 0; j < 4; ++j) {
      const float hv = (j == 0) ? h4.x : (j == 1) ? h4.y : (j == 2) ? h4.z : h4.w;
      a0 = fmaf(w[0][4 * k4 + j], hv, a0);
      a1 = fmaf(w[1][4 * k4 + j], hv, a1);
      a2 = fmaf(w[2][4 * k4 + j], hv, a2);
      a3 = fmaf(w[3][4 * k4 + j], hv, a3);
    }
  }
  return make_float4(a0, a1, a2, a3);
}

// ---------------------------------------------------------------------------
// Core stage: gates = Whh*h_own (G=4 x K/8, permuted partials) + add-terms.
// DRH: dword offset of destination h ring.
template <int SSELF, int SWA, int SWB, int NP, int XF, int PB, int PR1, int PR2, int DRH>
__device__ void core_stage(float* __restrict__ wsm, char* SB, int g) {
  const int tid = threadIdx.x;              // [0,1024)
  const int r0 = g * 8;
  float* gs   = (float*)SB;                 // [8 rows][8 kq][512 colp] = 131072 B
  float* hown = (float*)(SB + 131072);      // [8][128] = 4096 B

  u64* ws64 = (u64*)wsm;
  unsigned* flagb = (unsigned*)wsm + FLAGS;
  unsigned* Fself = flagb + (size_t)(SSELF * 32 + g) * 32;
  unsigned* Fh    = flagb + (size_t)(6 * 32 + g) * 32;
  unsigned ca = 0, cb = 0, ch = 0;

  // dot role: unit ud owns gate cols {ud+128q}, k-range [kq*16, kq*16+16)
  const int ud = tid & 127, kq = tid >> 7;
  float w[4][16];
  #pragma unroll
  for (int q = 0; q < 4; ++q)
    #pragma unroll
    for (int k = 0; k < 16; ++k)
      w[q][k] = wsm[(size_t)PB * 65536 + (size_t)(kq * 16 + k) * 512 + ud + 128 * q];

  // combine+activation role: (row, u)
  const int row = tid >> 7, u = tid & 127;
  float xw4[4], bs4[4];
  if (XF) {
    #pragma unroll
    for (int q = 0; q < 4; ++q) {
      xw4[q] = wsm[SCAL + q * 128 + u];
      bs4[q] = wsm[SCAL + 1536 + q * 128 + u];
    }
  }

  hown[tid & 1023] = 0.f;                   // 8*128 = 1024 = blockDim
  float cst = 0.f;
  __syncthreads();

  for (int t = 0; t < TT; ++t) {
    if (tid == 0) {
      if constexpr (SWA >= 0)
        wait_c(flagb + (size_t)(SWA * 32 + g) * 32, (unsigned)(t + 1), ca);
      if constexpr (SWB >= 0)
        wait_c(flagb + (size_t)(SWB * 32 + g) * 32, (unsigned)(t + 1), cb);
      unsigned ht = (t >= 15) ? (unsigned)(t - 14) : 0u;
      if (XF && t >= TSEQ && (unsigned)t > ht) ht = (unsigned)t;
      if (ht) wait_c(Fh, ht, ch);
    }
    __syncthreads();                 // B1: inputs granted
    const int slot = t & 15;

    // combine-role prefetch: ring add-terms as contiguous u64 pairs
    // (PERMUTED ring: col' = 4u + q), plus x for XF.
    float pa[4], pb[4], xr;
    if constexpr (NP >= 1) {
      u64 l0 = __hip_atomic_load(
          ws64 + (size_t)(PR1 / 2) + (size_t)(t & 7) * 65536 +
              (size_t)(r0 + row) * 256 + 2 * u,
          __ATOMIC_RELAXED, __HIP_MEMORY_SCOPE_AGENT);
      u64 l1 = __hip_atomic_load(
          ws64 + (size_t)(PR1 / 2) + (size_t)(t & 7) * 65536 +
              (size_t)(r0 + row) * 256 + 2 * u + 1,
          __ATOMIC_RELAXED, __HIP_MEMORY_SCOPE_AGENT);
      pa[0] = __builtin_bit_cast(float, (unsigned)(l0 & 0xffffffffu));
      pa[1] = __builtin_bit_cast(float, (unsigned)(l0 >> 32));
      pa[2] = __builtin_bit_cast(float, (unsigned)(l1 & 0xffffffffu));
      pa[3] = __builtin_bit_cast(float, (unsigned)(l1 >> 32));
    }
    if constexpr (NP == 2) {
      u64 l0 = __hip_atomic_load(
          ws64 + (size_t)(PR2 / 2) + (size_t)(t & 7) * 65536 +
              (size_t)(r0 + row) * 256 + 2 * u,
          __ATOMIC_RELAXED, __HIP_MEMORY_SCOPE_AGENT);
      u64 l1 = __hip_atomic_load(
          ws64 + (size_t)(PR2 / 2) + (size_t)(t & 7) * 65536 +
              (size_t)(r0 + row) * 256 + 2 * u + 1,
          __ATOMIC_RELAXED, __HIP_MEMORY_SCOPE_AGENT);
      pb[0] = __builtin_bit_cast(float, (unsigned)(l0 & 0xffffffffu));
      pb[1] = __builtin_bit_cast(float, (unsigned)(l0 >> 32));
      pb[2] = __builtin_bit_cast(float, (unsigned)(l1 & 0xffffffffu));
      pb[3] = __builtin_bit_cast(float, (unsigned)(l1 >> 32));
    }
    if (XF) {
      if (t < TSEQ) {
        xr = wsm[XT + (size_t)t * 256 + r0 + row];
      } else {
        unsigned uu = __hip_atomic_load(
            (unsigned*)wsm + RO + (size_t)((t - 1) & 15) * 256 + r0 + row,
            __ATOMIC_RELAXED, __HIP_MEMORY_SCOPE_AGENT);
        xr = __builtin_bit_cast(float, uu);
      }
    }

    // dot: per row accumulate-then-store (acc live range = 4)
    #pragma unroll
    for (int a = 0; a < 8; ++a) {
      const float4 acc = dot16_g4(w, hown + a * HH + kq * 16);
      *(float4*)&gs[a * 4096 + kq * 512 + 4 * ud] = acc;
    }
    __syncthreads();                 // B2: partials visible

    // fused combine + activation: sum 8 contiguous-b128 partials
    {
      float gv0, gv1, gv2, gv3;
      if constexpr (NP == 0) {
        gv0 = fmaf(xw4[0], xr, bs4[0]);
        gv1 = fmaf(xw4[1], xr, bs4[1]);
        gv2 = fmaf(xw4[2], xr, bs4[2]);
        gv3 = fmaf(xw4[3], xr, bs4[3]);
      } else if constexpr (NP == 1) {
        gv0 = pa[0]; gv1 = pa[1]; gv2 = pa[2]; gv3 = pa[3];
      } else {
        gv0 = pa[0] + pb[0]; gv1 = pa[1] + pb[1];
        gv2 = pa[2] + pb[2]; gv3 = pa[3] + pb[3];
      }
      #pragma unroll
      for (int p = 0; p < 8; ++p) {
        const float4 f = *(const float4*)&gs[row * 4096 + p * 512 + 4 * u];
        gv0 += f.x; gv1 += f.y; gv2 += f.z; gv3 += f.w;
      }
      const float c = sigmoidf_(gv1) * cst + sigmoidf_(gv0) * tanhf(gv2);
      cst = c;
      const float h = sigmoidf_(gv3) * tanhf(c);
      hown[row * HH + u] = h;
      __hip_atomic_store(
          (unsigned*)wsm + DRH + (size_t)slot * 32768 + (size_t)(r0 + row) * 128 + u,
          __builtin_bit_cast(unsigned, h),
          __ATOMIC_RELAXED, __HIP_MEMORY_SCOPE_AGENT);
    }
    __syncthreads();                 // B3: hown visible, stores drained
    if (tid == 0)
      __hip_atomic_fetch_add(Fself, 1u, __ATOMIC_RELAXED, __HIP_MEMORY_SCOPE_AGENT);
  }
}

// ---------------------------------------------------------------------------
// Helper stage: partial = [x-term+bias if XF] + Wpart * h_src(t) (G=4 x K/8,
// permuted partials); combine; publish PERMUTED to partial ring (u64 pairs).
// SC: DIRECT-CONSUMER stage id for the RP anti-dep (>= t-6, strict t-7).
template <int SSELF, int SW, int SC, int XF, int PB, int SI, int SRH64, int DRP>
__device__ void helper_stage(float* __restrict__ wsm, char* SB, int g) {
  const int tid = threadIdx.x;
  const int r0 = g * 8;
  float* ps  = (float*)SB;                  // [8][8][512] = 131072 B
  float* hin = (float*)(SB + 131072);       // [8][128] = 4096 B
  float* xs  = (float*)(SB + 135168);       // [8]

  u64* ws64 = (u64*)wsm;
  unsigned* flagb = (unsigned*)wsm + FLAGS;
  unsigned* Fself = flagb + (size_t)(SSELF * 32 + g) * 32;
  unsigned* Fw    = flagb + (size_t)(SW * 32 + g) * 32;
  unsigned* Fc    = flagb + (size_t)(SC * 32 + g) * 32;
  unsigned* Fhd   = flagb + (size_t)(6 * 32 + g) * 32;
  unsigned cw = 0, cc = 0, chd = 0;

  const int ud = tid & 127, kq = tid >> 7;
  float w[4][16];
  #pragma unroll
  for (int q = 0; q < 4; ++q)
    #pragma unroll
    for (int k = 0; k < 16; ++k)
      w[q][k] = wsm[(size_t)PB * 65536 + (size_t)(kq * 16 + k) * 512 + ud + 128 * q];

  const int row = tid >> 7, u = tid & 127;
  float xw4[4], bs4[4];
  if (XF) {
    #pragma unroll
    for (int q = 0; q < 4; ++q) {
      xw4[q] = wsm[SCAL + SI * 512 + q * 128 + u];
      bs4[q] = wsm[SCAL + 1536 + SI * 512 + q * 128 + u];
    }
  }
  __syncthreads();

  for (int t = 0; t < TT; ++t) {
    if (tid == 0) {
      wait_c(Fw, (unsigned)(t + 1), cw);
      if (t >= 7) wait_c(Fc, (unsigned)(t - 6), cc);
      if (XF && t >= TSEQ) wait_c(Fhd, (unsigned)t, chd);
    }
    __syncthreads();                 // B1: inputs granted
    const int slot = t & 15;

    if (XF) {
      if (tid < 8) {
        float xv;
        if (t < TSEQ) {
          xv = wsm[XT + (size_t)t * 256 + r0 + tid];
        } else {
          unsigned uu = __hip_atomic_load(
              (unsigned*)wsm + RO + (size_t)((t - 1) & 15) * 256 + r0 + tid,
              __ATOMIC_RELAXED, __HIP_MEMORY_SCOPE_AGENT);
          xv = __builtin_bit_cast(float, uu);
        }
        xs[tid] = xv;
      }
    }
    // stage h_src(t): 512 u64 / first 512 threads
    if (tid < 512) {
      const int a = tid >> 6, up = tid & 63;
      u64 v = __hip_atomic_load(
          ws64 + SRH64 + (size_t)slot * 16384 + (size_t)(r0 + a) * 64 + up,
          __ATOMIC_RELAXED, __HIP_MEMORY_SCOPE_AGENT);
      *(u64*)&hin[a * HH + up * 2] = v;
    }
    __syncthreads();                 // B2: hin (and xs) visible

    // dot: per row accumulate-then-store
    #pragma unroll
    for (int a = 0; a < 8; ++a) {
      const float4 acc = dot16_g4(w, hin + a * HH + kq * 16);
      *(float4*)&ps[a * 4096 + kq * 512 + 4 * ud] = acc;
    }
    __syncthreads();                 // B3: partials visible

    // combine + publish (PERMUTED ring cols 4u+q, as 2 u64 stores)
    {
      float v0, v1, v2, v3;
      if (XF) {
        const float xv = xs[row];
        v0 = fmaf(xw4[0], xv, bs4[0]);
        v1 = fmaf(xw4[1], xv, bs4[1]);
        v2 = fmaf(xw4[2], xv, bs4[2]);
        v3 = fmaf(xw4[3], xv, bs4[3]);
      } else {
        v0 = v1 = v2 = v3 = 0.f;
      }
      #pragma unroll
      for (int p = 0; p < 8; ++p) {
        const float4 f = *(const float4*)&ps[row * 4096 + p * 512 + 4 * u];
        v0 += f.x; v1 += f.y; v2 += f.z; v3 += f.w;
      }
      const u64 s0 = ((u64)__builtin_bit_cast(unsigned, v1) << 32) |
                     (u64)__builtin_bit_cast(unsigned, v0);
      const u64 s1 = ((u64)__builtin_bit_cast(unsigned, v3) << 32) |
                     (u64)__builtin_bit_cast(unsigned, v2);
      __hip_atomic_store(
          ws64 + (size_t)(DRP / 2) + (size_t)(t & 7) * 65536 +
              (size_t)(r0 + row) * 256 + 2 * u, s0,
          __ATOMIC_RELAXED, __HIP_MEMORY_SCOPE_AGENT);
      __hip_atomic_store(
          ws64 + (size_t)(DRP / 2) + (size_t)(t & 7) * 65536 +
              (size_t)(r0 + row) * 256 + 2 * u + 1, s1,
          __ATOMIC_RELAXED, __HIP_MEMORY_SCOPE_AGENT);
    }
    __syncthreads();                 // B4: ring stores drained
    if (tid == 0)
      __hip_atomic_fetch_add(Fself, 1u, __ATOMIC_RELAXED, __HIP_MEMORY_SCOPE_AGENT);
  }
}

// ---------------------------------------------------------------------------
__device__ void head_stage(float* __restrict__ wsm, char* SB, int g,
                           float* __restrict__ out) {
  const int tid = threadIdx.x;
  const int r0 = g * 8;
  float* hin  = (float*)SB;                 // [3][8][128] = 12288 B
  float* obuf = (float*)(SB + 12288);       // [8][32]

  u64* ws64 = (u64*)wsm;
  unsigned* flagb = (unsigned*)wsm + FLAGS;
  unsigned* Fself = flagb + (size_t)(6 * 32 + g) * 32;
  unsigned* Fc3   = flagb + (size_t)(5 * 32 + g) * 32;
  unsigned c3c = 0;

  const int row = (tid >> 6) & 7, lane = tid & 63;
  float wlr[6];
  #pragma unroll
  for (int q = 0; q < 6; ++q) wlr[q] = wsm[WLIN + 1 + lane + 64 * q];
  const float wl0 = wsm[WLIN];
  const float blv = wsm[WLIN + 385];
  float xv = wsm[XT + r0 + row];

  for (int t = 0; t < TT; ++t) {
    if (tid == 0) wait_c(Fc3, (unsigned)(t + 1), c3c);
    __syncthreads();                 // B1
    const int slot = t & 15;

    #pragma unroll
    for (int i = 0; i < 2; ++i) {
      const int idx = tid + i * 1024;       // 0..2047, use 0..1535
      if (idx < 1536) {
        const int s = idx >> 9, rem = idx & 511;
        const int a = rem >> 6, up = rem & 63;
        const size_t base = (s == 0) ? (size_t)RH1_64 : (s == 1) ? (size_t)RH2_64 : (size_t)RH3_64;
        u64 v = __hip_atomic_load(
            ws64 + base + (size_t)slot * 16384 + (size_t)(r0 + a) * 64 + up,
            __ATOMIC_RELAXED, __HIP_MEMORY_SCOPE_AGENT);
        *(u64*)&hin[(s * 8 + a) * HH + up * 2] = v;
      }
    }
    __syncthreads();                 // B2

    if (tid < 512) {
      float s = 0.f;
      #pragma unroll
      for (int q = 0; q < 6; ++q) {
        const int j = lane + 64 * q;        // 0..383
        const int si = j >> 7, uu = j & 127;
        s = fmaf(wlr[q], hin[(si * 8 + row) * HH + uu], s);
      }
      #pragma unroll
      for (int off = 32; off > 0; off >>= 1) s += __shfl_down(s, off, 64);
      if (lane == 0) {
        const float o = s + fmaf(wl0, xv, blv);
        obuf[row * 32 + (t & 31)] = o;
        __hip_atomic_store((unsigned*)wsm + RO + (size_t)slot * 256 + r0 + row,
                           __builtin_bit_cast(unsigned, o),
                           __ATOMIC_RELAXED, __HIP_MEMORY_SCOPE_AGENT);
        xv = (t + 1 < TSEQ) ? wsm[XT + (size_t)(t + 1) * 256 + r0 + row] : o;
      }
    }
    __syncthreads();                 // B3: o-store + obuf drained
    if (tid == 0)
      __hip_atomic_fetch_add(Fself, 1u, __ATOMIC_RELAXED, __HIP_MEMORY_SCOPE_AGENT);

    if ((t & 31) == 31) {
      const int tb = t - 31;
      if (tid < 256) {
        const int a = tid >> 5, m = tid & 31;
        out[(size_t)(r0 + a) * TT + tb + m] = obuf[a * 32 + m];
      }
    }
  }
}

// ---------------------------------------------------------------------------
__global__ __launch_bounds__(1024)
void lstm_kernel(float* __restrict__ wsm, float* __restrict__ out) {
  __shared__ __align__(16) char SB[135232];
  const int s = blockIdx.x >> 5, g = blockIdx.x & 31;
  switch (s) {
    case 0: core_stage<0, -1, -1, 0, 1, 0, 0, 0, RH1>(wsm, SB, g); break;
    case 1: helper_stage<1, 0, 2, 1, 1, 1, RH1_64, RP2>(wsm, SB, g); break;
    case 2: core_stage<2, 1, -1, 1, 0, 2, RP2, 0, RH2>(wsm, SB, g); break;
    case 3: helper_stage<3, 0, 5, 1, 3, 2, RH1_64, RP3A>(wsm, SB, g); break;
    case 4: helper_stage<4, 2, 5, 0, 4, 0, RH2_64, RP3B>(wsm, SB, g); break;
    case 5: core_stage<5, 3, 4, 2, 0, 5, RP3A, RP3B, RH3>(wsm, SB, g); break;
    default: head_stage(wsm, SB, g, out); break;
  }
}

// ---------------------------------------------------------------------------
extern "C" void kernel_launch(void* const* d_in, const int* in_sizes, int n_in,
                              void* d_out, int out_size, void* d_ws, size_t ws_size,
                              hipStream_t stream) {
  const float* x    = (const float*)d_in[0];
  const float* Wih1 = (const float*)d_in[1];
  const float* Whh1 = (const float*)d_in[2];
  const float* bih1 = (const float*)d_in[3];
  const float* bhh1 = (const float*)d_in[4];
  const float* Wih2 = (const float*)d_in[5];
  const float* Whh2 = (const float*)d_in[6];
  const float* bih2 = (const float*)d_in[7];
  const float* bhh2 = (const float*)d_in[8];
  const float* Wih3 = (const float*)d_in[9];
  const float* Whh3 = (const float*)d_in[10];
  const float* bih3 = (const float*)d_in[11];
  const float* bhh3 = (const float*)d_in[12];
  const float* Wlin = (const float*)d_in[13];
  const float* blin = (const float*)d_in[14];
  float* ws  = (float*)d_ws;
  float* out = (float*)d_out;

  prep_kernel<<<PREP_TOT / 256, 256, 0, stream>>>(
      x, Wih1, Whh1, bih1, bhh1, Wih2, Whh2, bih2, bhh2,
      Wih3, Whh3, bih3, bhh3, Wlin, blin, ws);
  lstm_kernel<<<224, THR, 0, stream>>>(ws, out);
}

// Round 22
// 5760.197 us; speedup vs baseline: 5.2005x; 1.0994x over previous
//
#include <hip/hip_runtime.h>
#include <math.h>

// DenseLSTMForecast: B=256, T=1024, H=128, FUTURE=32.
// R16 (2nd submit; round 21 hit GPUAcquisitionTimeout, never measured).
// R16: R15 + half-split RP permutation (lane-consecutive u64 ring stores).
// R15 post-mortem (6333us best, step 14.4k cy, VALU 32%): G=4 gate-
// contiguous dot confirmed the LDS ladder (2048->1024->~768 b128 gave
// 19.3k->15.5k->14.4k). BUT WRITE_SIZE jumped 2.04->3.67GB: delta =
// EXACTLY the RP ring volume (1.62GB) => RP stores counted twice (RMW /
// non-merging partial-line writes). Cause: per-thread u64 stores at
// indices {2u, 2u+1} are per-INSTRUCTION stride-2 across the wave —
// each instruction covers half of every cache line.
// Fix (single variable): half-split permutation — gates{0,1} stored at
// col u, gates{2,3} at col 128+u. Each store instruction is then
// lane-consecutive (contiguous 512B/wave) -> full-line coalescing.
// Core-combine reader decodes symmetrically (ring internal-only).
// Everything else byte-identical to measured R15: G=4 dot (512 b128
// reads), permuted LDS partials, fused combine+activation, 1024-thr
// blocks, sync = R13 (tid0 poll + B1, consumer-gated helper anti-deps).
// Geometry: 32 groups x 8 rows, 224 WGs, 7 stages:
//   s0 c1-core   : g1 = xw1*x+b1 + Whh1*h1           -> RH1 ring
//   s1 c2-helper : p2 = xw2*x+b2 + Wih2[:,1:]*h1(t)  -> RP2 ring (half-split)
//   s2 c2-core   : g2 = p2 + Whh2*h2                 -> RH2 ring
//   s3 c3-helperA: pA = xw3*x+b3 + Wih3[:,1:129]*h1  -> RP3A ring (half-split)
//   s4 c3-helperB: pB = Wih3[:,129:257]*h2           -> RP3B ring (half-split)
//   s5 c3-core   : g3 = pA+pB + Whh3*h3              -> RH3 ring
//   s6 head      : o = Wlin.[x,h1,h2,h3]+b           -> RO ring + out
// Prediction: WRITE_SIZE 3.67->~2.05GB; dur 6333 -> 5600-6100us.
// Null (dur flat, WRITE drops): store path not critical -> residual is
// barrier/flag serialization -> merge helper B3/B4 + stage fusion next.

#define TSEQ 1024
#define HH   128
#define TT   1056
#define THR  1024

// ---- ws dword offsets (identical to R7) ----
#define PLANES   0                 // 6 planes x [128 k][512 g] fp32
#define SCAL     393216            // xw1,xw2,xw3,bs1,bs2,bs3 (512 each)
#define WLIN     396288            // Wlin[0..384], [385]=b_lin, pad 512
#define XT       396800            // x transposed [1024][256]
#define RH1      658944            // h rings: [16][256][128] fp32
#define RH2      1183232
#define RH3      1707520
#define RO       2231808           // o ring [16][256] fp32
#define RP2      2235904           // partial rings: [8][256][512] fp32 (half-split perm)
#define RP3A     3284480
#define RP3B     4333056
#define FLAGS    5381632           // 224 x 32-dword lines
#define PREP_TOT 666112            // 658944 + 7168 (flags zeroing)

#define RH1_64 (RH1/2)
#define RH2_64 (RH2/2)
#define RH3_64 (RH3/2)

typedef unsigned long long u64;

__device__ __forceinline__ float sigmoidf_(float v) {
  return 1.0f / (1.0f + expf(-v));
}

__device__ __forceinline__ void wait_c(unsigned* p, unsigned tgt, unsigned& cached) {
  if (cached >= tgt) return;
  unsigned v = __hip_atomic_load(p, __ATOMIC_ACQUIRE, __HIP_MEMORY_SCOPE_AGENT);
  while (v < tgt) {
    __builtin_amdgcn_s_sleep(1);
    v = __hip_atomic_load(p, __ATOMIC_ACQUIRE, __HIP_MEMORY_SCOPE_AGENT);
  }
  cached = v;
}

// ---------------------------------------------------------------------------
__global__ void prep_kernel(const float* __restrict__ x,
                            const float* __restrict__ Wih1, const float* __restrict__ Whh1,
                            const float* __restrict__ bih1, const float* __restrict__ bhh1,
                            const float* __restrict__ Wih2, const float* __restrict__ Whh2,
                            const float* __restrict__ bih2, const float* __restrict__ bhh2,
                            const float* __restrict__ Wih3, const float* __restrict__ Whh3,
                            const float* __restrict__ bih3, const float* __restrict__ bhh3,
                            const float* __restrict__ Wlin, const float* __restrict__ blin,
                            float* __restrict__ ws) {
  int idx = blockIdx.x * 256 + threadIdx.x;
  if (idx < SCAL) {
    int p = idx >> 16;            // plane
    int rem = idx & 65535;
    int k = rem >> 9, g = rem & 511;
    float v;
    switch (p) {
      case 0:  v = Whh1[g * HH + k];         break;
      case 1:  v = Wih2[g * 129 + 1 + k];    break;
      case 2:  v = Whh2[g * HH + k];         break;
      case 3:  v = Wih3[g * 257 + 1 + k];    break;
      case 4:  v = Wih3[g * 257 + 129 + k];  break;
      default: v = Whh3[g * HH + k];         break;
    }
    ws[idx] = v;
  } else if (idx < WLIN) {
    int r = idx - SCAL;
    float v;
    if      (r < 512)  v = Wih1[r];
    else if (r < 1024) v = Wih2[(r - 512) * 129];
    else if (r < 1536) v = Wih3[(r - 1024) * 257];
    else if (r < 2048) v = bih1[r - 1536] + bhh1[r - 1536];
    else if (r < 2560) v = bih2[r - 2048] + bhh2[r - 2048];
    else               v = bih3[r - 2560] + bhh3[r - 2560];
    ws[idx] = v;
  } else if (idx < XT) {
    int j = idx - WLIN;
    ws[idx] = (j < 385) ? Wlin[j] : (j == 385 ? blin[0] : 0.0f);
  } else if (idx < RH1) {
    int j = idx - XT;
    int t = j >> 8, r = j & 255;
    ws[idx] = x[r * TSEQ + t];
  } else if (idx < PREP_TOT) {
    ws[FLAGS + (idx - RH1)] = 0.0f;   // zero flag lines (ws is poisoned)
  }
}

// ---------------------------------------------------------------------------
// G=4 K/8 dot for one row: 16 k-values, 4 gates of unit ud.
// hb pre-offset to the row base + kq*16. Returns acc as float4 (gate order).
__device__ __forceinline__ float4 dot16_g4(const float w[4][16],
                                           const float* __restrict__ hb) {
  float a0 = 0.f, a1 = 0.f, a2 = 0.f, a3 = 0.f;
  #pragma unroll
  for (int k4 = 0; k4 < 4; ++k4) {
    const float4 h4 = *(const float4*)&hb[k4 * 4];
    #pragma unroll
    for (int j = 0; j < 4; ++j) {
      const float hv = (j == 0) ? h4.x : (j == 1) ? h4.y : (j == 2) ? h4.z : h4.w;
      a0 = fmaf(w[0][4 * k4 + j], hv, a0);
      a1 = fmaf(w[1][4 * k4 + j], hv, a1);
      a2 = fmaf(w[2][4 * k4 + j], hv, a2);
      a3 = fmaf(w[3][4 * k4 + j], hv, a3);
    }
  }
  return make_float4(a0, a1, a2, a3);
}

// ---------------------------------------------------------------------------
// Core stage: gates = Whh*h_own (G=4 x K/8, permuted partials) + add-terms.
// DRH: dword offset of destination h ring.
template <int SSELF, int SWA, int SWB, int NP, int XF, int PB, int PR1, int PR2, int DRH>
__device__ void core_stage(float* __restrict__ wsm, char* SB, int g) {
  const int tid = threadIdx.x;              // [0,1024)
  const int r0 = g * 8;
  float* gs   = (float*)SB;                 // [8 rows][8 kq][512 colp] = 131072 B
  float* hown = (float*)(SB + 131072);      // [8][128] = 4096 B

  u64* ws64 = (u64*)wsm;
  unsigned* flagb = (unsigned*)wsm + FLAGS;
  unsigned* Fself = flagb + (size_t)(SSELF * 32 + g) * 32;
  unsigned* Fh    = flagb + (size_t)(6 * 32 + g) * 32;
  unsigned ca = 0, cb = 0, ch = 0;

  // dot role: unit ud owns gate cols {ud+128q}, k-range [kq*16, kq*16+16)
  const int ud = tid & 127, kq = tid >> 7;
  float w[4][16];
  #pragma unroll
  for (int q = 0; q < 4; ++q)
    #pragma unroll
    for (int k = 0; k < 16; ++k)
      w[q][k] = wsm[(size_t)PB * 65536 + (size_t)(kq * 16 + k) * 512 + ud + 128 * q];

  // combine+activation role: (row, u)
  const int row = tid >> 7, u = tid & 127;
  float xw4[4], bs4[4];
  if (XF) {
    #pragma unroll
    for (int q = 0; q < 4; ++q) {
      xw4[q] = wsm[SCAL + q * 128 + u];
      bs4[q] = wsm[SCAL + 1536 + q * 128 + u];
    }
  }

  hown[tid & 1023] = 0.f;                   // 8*128 = 1024 = blockDim
  float cst = 0.f;
  __syncthreads();

  for (int t = 0; t < TT; ++t) {
    if (tid == 0) {
      if constexpr (SWA >= 0)
        wait_c(flagb + (size_t)(SWA * 32 + g) * 32, (unsigned)(t + 1), ca);
      if constexpr (SWB >= 0)
        wait_c(flagb + (size_t)(SWB * 32 + g) * 32, (unsigned)(t + 1), cb);
      unsigned ht = (t >= 15) ? (unsigned)(t - 14) : 0u;
      if (XF && t >= TSEQ && (unsigned)t > ht) ht = (unsigned)t;
      if (ht) wait_c(Fh, ht, ch);
    }
    __syncthreads();                 // B1: inputs granted
    const int slot = t & 15;

    // combine-role prefetch: ring add-terms (HALF-SPLIT permutation):
    // gates{0,1} packed at u64 col u; gates{2,3} at u64 col 128+u.
    float pa[4], pb[4], xr;
    if constexpr (NP >= 1) {
      u64 l0 = __hip_atomic_load(
          ws64 + (size_t)(PR1 / 2) + (size_t)(t & 7) * 65536 +
              (size_t)(r0 + row) * 256 + u,
          __ATOMIC_RELAXED, __HIP_MEMORY_SCOPE_AGENT);
      u64 l1 = __hip_atomic_load(
          ws64 + (size_t)(PR1 / 2) + (size_t)(t & 7) * 65536 +
              (size_t)(r0 + row) * 256 + 128 + u,
          __ATOMIC_RELAXED, __HIP_MEMORY_SCOPE_AGENT);
      pa[0] = __builtin_bit_cast(float, (unsigned)(l0 & 0xffffffffu));
      pa[1] = __builtin_bit_cast(float, (unsigned)(l0 >> 32));
      pa[2] = __builtin_bit_cast(float, (unsigned)(l1 & 0xffffffffu));
      pa[3] = __builtin_bit_cast(float, (unsigned)(l1 >> 32));
    }
    if constexpr (NP == 2) {
      u64 l0 = __hip_atomic_load(
          ws64 + (size_t)(PR2 / 2) + (size_t)(t & 7) * 65536 +
              (size_t)(r0 + row) * 256 + u,
          __ATOMIC_RELAXED, __HIP_MEMORY_SCOPE_AGENT);
      u64 l1 = __hip_atomic_load(
          ws64 + (size_t)(PR2 / 2) + (size_t)(t & 7) * 65536 +
              (size_t)(r0 + row) * 256 + 128 + u,
          __ATOMIC_RELAXED, __HIP_MEMORY_SCOPE_AGENT);
      pb[0] = __builtin_bit_cast(float, (unsigned)(l0 & 0xffffffffu));
      pb[1] = __builtin_bit_cast(float, (unsigned)(l0 >> 32));
      pb[2] = __builtin_bit_cast(float, (unsigned)(l1 & 0xffffffffu));
      pb[3] = __builtin_bit_cast(float, (unsigned)(l1 >> 32));
    }
    if (XF) {
      if (t < TSEQ) {
        xr = wsm[XT + (size_t)t * 256 + r0 + row];
      } else {
        unsigned uu = __hip_atomic_load(
            (unsigned*)wsm + RO + (size_t)((t - 1) & 15) * 256 + r0 + row,
            __ATOMIC_RELAXED, __HIP_MEMORY_SCOPE_AGENT);
        xr = __builtin_bit_cast(float, uu);
      }
    }

    // dot: per row accumulate-then-store (acc live range = 4)
    #pragma unroll
    for (int a = 0; a < 8; ++a) {
      const float4 acc = dot16_g4(w, hown + a * HH + kq * 16);
      *(float4*)&gs[a * 4096 + kq * 512 + 4 * ud] = acc;
    }
    __syncthreads();                 // B2: partials visible

    // fused combine + activation: sum 8 contiguous-b128 partials
    {
      float gv0, gv1, gv2, gv3;
      if constexpr (NP == 0) {
        gv0 = fmaf(xw4[0], xr, bs4[0]);
        gv1 = fmaf(xw4[1], xr, bs4[1]);
        gv2 = fmaf(xw4[2], xr, bs4[2]);
        gv3 = fmaf(xw4[3], xr, bs4[3]);
      } else if constexpr (NP == 1) {
        gv0 = pa[0]; gv1 = pa[1]; gv2 = pa[2]; gv3 = pa[3];
      } else {
        gv0 = pa[0] + pb[0]; gv1 = pa[1] + pb[1];
        gv2 = pa[2] + pb[2]; gv3 = pa[3] + pb[3];
      }
      #pragma unroll
      for (int p = 0; p < 8; ++p) {
        const float4 f = *(const float4*)&gs[row * 4096 + p * 512 + 4 * u];
        gv0 += f.x; gv1 += f.y; gv2 += f.z; gv3 += f.w;
      }
      const float c = sigmoidf_(gv1) * cst + sigmoidf_(gv0) * tanhf(gv2);
      cst = c;
      const float h = sigmoidf_(gv3) * tanhf(c);
      hown[row * HH + u] = h;
      __hip_atomic_store(
          (unsigned*)wsm + DRH + (size_t)slot * 32768 + (size_t)(r0 + row) * 128 + u,
          __builtin_bit_cast(unsigned, h),
          __ATOMIC_RELAXED, __HIP_MEMORY_SCOPE_AGENT);
    }
    __syncthreads();                 // B3: hown visible, stores drained
    if (tid == 0)
      __hip_atomic_fetch_add(Fself, 1u, __ATOMIC_RELAXED, __HIP_MEMORY_SCOPE_AGENT);
  }
}

// ---------------------------------------------------------------------------
// Helper stage: partial = [x-term+bias if XF] + Wpart * h_src(t) (G=4 x K/8,
// permuted partials); combine; publish HALF-SPLIT to partial ring:
// gates{0,1} -> u64 col u (lane-consecutive), gates{2,3} -> u64 col 128+u.
// SC: DIRECT-CONSUMER stage id for the RP anti-dep (>= t-6, strict t-7).
template <int SSELF, int SW, int SC, int XF, int PB, int SI, int SRH64, int DRP>
__device__ void helper_stage(float* __restrict__ wsm, char* SB, int g) {
  const int tid = threadIdx.x;
  const int r0 = g * 8;
  float* ps  = (float*)SB;                  // [8][8][512] = 131072 B
  float* hin = (float*)(SB + 131072);       // [8][128] = 4096 B
  float* xs  = (float*)(SB + 135168);       // [8]

  u64* ws64 = (u64*)wsm;
  unsigned* flagb = (unsigned*)wsm + FLAGS;
  unsigned* Fself = flagb + (size_t)(SSELF * 32 + g) * 32;
  unsigned* Fw    = flagb + (size_t)(SW * 32 + g) * 32;
  unsigned* Fc    = flagb + (size_t)(SC * 32 + g) * 32;
  unsigned* Fhd   = flagb + (size_t)(6 * 32 + g) * 32;
  unsigned cw = 0, cc = 0, chd = 0;

  const int ud = tid & 127, kq = tid >> 7;
  float w[4][16];
  #pragma unroll
  for (int q = 0; q < 4; ++q)
    #pragma unroll
    for (int k = 0; k < 16; ++k)
      w[q][k] = wsm[(size_t)PB * 65536 + (size_t)(kq * 16 + k) * 512 + ud + 128 * q];

  const int row = tid >> 7, u = tid & 127;
  float xw4[4], bs4[4];
  if (XF) {
    #pragma unroll
    for (int q = 0; q < 4; ++q) {
      xw4[q] = wsm[SCAL + SI * 512 + q * 128 + u];
      bs4[q] = wsm[SCAL + 1536 + SI * 512 + q * 128 + u];
    }
  }
  __syncthreads();

  for (int t = 0; t < TT; ++t) {
    if (tid == 0) {
      wait_c(Fw, (unsigned)(t + 1), cw);
      if (t >= 7) wait_c(Fc, (unsigned)(t - 6), cc);
      if (XF && t >= TSEQ) wait_c(Fhd, (unsigned)t, chd);
    }
    __syncthreads();                 // B1: inputs granted
    const int slot = t & 15;

    if (XF) {
      if (tid < 8) {
        float xv;
        if (t < TSEQ) {
          xv = wsm[XT + (size_t)t * 256 + r0 + tid];
        } else {
          unsigned uu = __hip_atomic_load(
              (unsigned*)wsm + RO + (size_t)((t - 1) & 15) * 256 + r0 + tid,
              __ATOMIC_RELAXED, __HIP_MEMORY_SCOPE_AGENT);
          xv = __builtin_bit_cast(float, uu);
        }
        xs[tid] = xv;
      }
    }
    // stage h_src(t): 512 u64 / first 512 threads
    if (tid < 512) {
      const int a = tid >> 6, up = tid & 63;
      u64 v = __hip_atomic_load(
          ws64 + SRH64 + (size_t)slot * 16384 + (size_t)(r0 + a) * 64 + up,
          __ATOMIC_RELAXED, __HIP_MEMORY_SCOPE_AGENT);
      *(u64*)&hin[a * HH + up * 2] = v;
    }
    __syncthreads();                 // B2: hin (and xs) visible

    // dot: per row accumulate-then-store
    #pragma unroll
    for (int a = 0; a < 8; ++a) {
      const float4 acc = dot16_g4(w, hin + a * HH + kq * 16);
      *(float4*)&ps[a * 4096 + kq * 512 + 4 * ud] = acc;
    }
    __syncthreads();                 // B3: partials visible

    // combine + publish (HALF-SPLIT ring: lane-consecutive u64 stores)
    {
      float v0, v1, v2, v3;
      if (XF) {
        const float xv = xs[row];
        v0 = fmaf(xw4[0], xv, bs4[0]);
        v1 = fmaf(xw4[1], xv, bs4[1]);
        v2 = fmaf(xw4[2], xv, bs4[2]);
        v3 = fmaf(xw4[3], xv, bs4[3]);
      } else {
        v0 = v1 = v2 = v3 = 0.f;
      }
      #pragma unroll
      for (int p = 0; p < 8; ++p) {
        const float4 f = *(const float4*)&ps[row * 4096 + p * 512 + 4 * u];
        v0 += f.x; v1 += f.y; v2 += f.z; v3 += f.w;
      }
      const u64 s0 = ((u64)__builtin_bit_cast(unsigned, v1) << 32) |
                     (u64)__builtin_bit_cast(unsigned, v0);
      const u64 s1 = ((u64)__builtin_bit_cast(unsigned, v3) << 32) |
                     (u64)__builtin_bit_cast(unsigned, v2);
      __hip_atomic_store(
          ws64 + (size_t)(DRP / 2) + (size_t)(t & 7) * 65536 +
              (size_t)(r0 + row) * 256 + u, s0,
          __ATOMIC_RELAXED, __HIP_MEMORY_SCOPE_AGENT);
      __hip_atomic_store(
          ws64 + (size_t)(DRP / 2) + (size_t)(t & 7) * 65536 +
              (size_t)(r0 + row) * 256 + 128 + u, s1,
          __ATOMIC_RELAXED, __HIP_MEMORY_SCOPE_AGENT);
    }
    __syncthreads();                 // B4: ring stores drained
    if (tid == 0)
      __hip_atomic_fetch_add(Fself, 1u, __ATOMIC_RELAXED, __HIP_MEMORY_SCOPE_AGENT);
  }
}

// ---------------------------------------------------------------------------
__device__ void head_stage(float* __restrict__ wsm, char* SB, int g,
                           float* __restrict__ out) {
  const int tid = threadIdx.x;
  const int r0 = g * 8;
  float* hin  = (float*)SB;                 // [3][8][128] = 12288 B
  float* obuf = (float*)(SB + 12288);       // [8][32]

  u64* ws64 = (u64*)wsm;
  unsigned* flagb = (unsigned*)wsm + FLAGS;
  unsigned* Fself = flagb + (size_t)(6 * 32 + g) * 32;
  unsigned* Fc3   = flagb + (size_t)(5 * 32 + g) * 32;
  unsigned c3c = 0;

  const int row = (tid >> 6) & 7, lane = tid & 63;
  float wlr[6];
  #pragma unroll
  for (int q = 0; q < 6; ++q) wlr[q] = wsm[WLIN + 1 + lane + 64 * q];
  const float wl0 = wsm[WLIN];
  const float blv = wsm[WLIN + 385];
  float xv = wsm[XT + r0 + row];

  for (int t = 0; t < TT; ++t) {
    if (tid == 0) wait_c(Fc3, (unsigned)(t + 1), c3c);
    __syncthreads();                 // B1
    const int slot = t & 15;

    #pragma unroll
    for (int i = 0; i < 2; ++i) {
      const int idx = tid + i * 1024;       // 0..2047, use 0..1535
      if (idx < 1536) {
        const int s = idx >> 9, rem = idx & 511;
        const int a = rem >> 6, up = rem & 63;
        const size_t base = (s == 0) ? (size_t)RH1_64 : (s == 1) ? (size_t)RH2_64 : (size_t)RH3_64;
        u64 v = __hip_atomic_load(
            ws64 + base + (size_t)slot * 16384 + (size_t)(r0 + a) * 64 + up,
            __ATOMIC_RELAXED, __HIP_MEMORY_SCOPE_AGENT);
        *(u64*)&hin[(s * 8 + a) * HH + up * 2] = v;
      }
    }
    __syncthreads();                 // B2

    if (tid < 512) {
      float s = 0.f;
      #pragma unroll
      for (int q = 0; q < 6; ++q) {
        const int j = lane + 64 * q;        // 0..383
        const int si = j >> 7, uu = j & 127;
        s = fmaf(wlr[q], hin[(si * 8 + row) * HH + uu], s);
      }
      #pragma unroll
      for (int off = 32; off > 0; off >>= 1) s += __shfl_down(s, off, 64);
      if (lane == 0) {
        const float o = s + fmaf(wl0, xv, blv);
        obuf[row * 32 + (t & 31)] = o;
        __hip_atomic_store((unsigned*)wsm + RO + (size_t)slot * 256 + r0 + row,
                           __builtin_bit_cast(unsigned, o),
                           __ATOMIC_RELAXED, __HIP_MEMORY_SCOPE_AGENT);
        xv = (t + 1 < TSEQ) ? wsm[XT + (size_t)(t + 1) * 256 + r0 + row] : o;
      }
    }
    __syncthreads();                 // B3: o-store + obuf drained
    if (tid == 0)
      __hip_atomic_fetch_add(Fself, 1u, __ATOMIC_RELAXED, __HIP_MEMORY_SCOPE_AGENT);

    if ((t & 31) == 31) {
      const int tb = t - 31;
      if (tid < 256) {
        const int a = tid >> 5, m = tid & 31;
        out[(size_t)(r0 + a) * TT + tb + m] = obuf[a * 32 + m];
      }
    }
  }
}

// ---------------------------------------------------------------------------
__global__ __launch_bounds__(1024)
void lstm_kernel(float* __restrict__ wsm, float* __restrict__ out) {
  __shared__ __align__(16) char SB[135232];
  const int s = blockIdx.x >> 5, g = blockIdx.x & 31;
  switch (s) {
    case 0: core_stage<0, -1, -1, 0, 1, 0, 0, 0, RH1>(wsm, SB, g); break;
    case 1: helper_stage<1, 0, 2, 1, 1, 1, RH1_64, RP2>(wsm, SB, g); break;
    case 2: core_stage<2, 1, -1, 1, 0, 2, RP2, 0, RH2>(wsm, SB, g); break;
    case 3: helper_stage<3, 0, 5, 1, 3, 2, RH1_64, RP3A>(wsm, SB, g); break;
    case 4: helper_stage<4, 2, 5, 0, 4, 0, RH2_64, RP3B>(wsm, SB, g); break;
    case 5: core_stage<5, 3, 4, 2, 0, 5, RP3A, RP3B, RH3>(wsm, SB, g); break;
    default: head_stage(wsm, SB, g, out); break;
  }
}

// ---------------------------------------------------------------------------
extern "C" void kernel_launch(void* const* d_in, const int* in_sizes, int n_in,
                              void* d_out, int out_size, void* d_ws, size_t ws_size,
                              hipStream_t stream) {
  const float* x    = (const float*)d_in[0];
  const float* Wih1 = (const float*)d_in[1];
  const float* Whh1 = (const float*)d_in[2];
  const float* bih1 = (const float*)d_in[3];
  const float* bhh1 = (const float*)d_in[4];
  const float* Wih2 = (const float*)d_in[5];
  const float* Whh2 = (const float*)d_in[6];
  const float* bih2 = (const float*)d_in[7];
  const float* bhh2 = (const float*)d_in[8];
  const float* Wih3 = (const float*)d_in[9];
  const float* Whh3 = (const float*)d_in[10];
  const float* bih3 = (const float*)d_in[11];
  const float* bhh3 = (const float*)d_in[12];
  const float* Wlin = (const float*)d_in[13];
  const float* blin = (const float*)d_in[14];
  float* ws  = (float*)d_ws;
  float* out = (float*)d_out;

  prep_kernel<<<PREP_TOT / 256, 256, 0, stream>>>(
      x, Wih1, Whh1, bih1, bhh1, Wih2, Whh2, bih2, bhh2,
      Wih3, Whh3, bih3, bhh3, Wlin, blin, ws);
  lstm_kernel<<<224, THR, 0, stream>>>(ws, out);
}